// Round 3
// baseline (1122.947 us; speedup 1.0000x reference)
//
#include <hip/hip_runtime.h>
#include <math.h>

#define N_NODES 100000
#define E_EDGES 1600000
#define E_TOT   (E_EDGES + N_NODES)
#define G_GRAPHS 64
#define IN_DIM 256
#define HID 64
#define HEADS 4
#define D1 256            // HEADS*HID
#define NEG_SLOPE 0.2f
#define SCAN_B 1024
#define CHUNK2 8          // nodes per wave in agg2

// ---------------- fp32 tiled GEMM: C[M,Nc] = A[M,K] @ B[K,Nc] ----------------
// BMxBN tile, 256 threads, TMxTN microtile (split row/col groups at +64 to keep
// LDS reads 2-way-max bank aliased = free). K must be a multiple of 16.
template<int BM, int BN, int TM, int TN>
__global__ __launch_bounds__(256) void gemm_tiled(const float* __restrict__ A,
                                                  const float* __restrict__ B,
                                                  float* __restrict__ C,
                                                  int M, int K, int Nc)
{
    __shared__ float AsT[16][BM + 4];   // [k][m]
    __shared__ float Bs[16][BN + 4];    // [k][n]
    const int tid = threadIdx.x;
    const int tx = tid & 15, ty = tid >> 4;
    const int bm = blockIdx.y * BM, bn = blockIdx.x * BN;
    float acc[TM][TN] = {};

    const int A_F4 = BM * 4;   // float4s in A tile (BM rows x 16 k)
    const int B_F4 = BN * 4;   // float4s in B tile (16 k x BN cols)

    for (int k0 = 0; k0 < K; k0 += 16) {
        // stage A transposed: float4 f -> row f>>2, kq (f&3)*4
#pragma unroll
        for (int f = tid; f < A_F4; f += 256) {
            int row = f >> 2, kq = (f & 3) * 4;
            int m = bm + row;
            float4 av = make_float4(0.f, 0.f, 0.f, 0.f);
            if (m < M) av = *(const float4*)(A + (size_t)m * K + k0 + kq);
            AsT[kq + 0][row] = av.x;
            AsT[kq + 1][row] = av.y;
            AsT[kq + 2][row] = av.z;
            AsT[kq + 3][row] = av.w;
        }
        // stage B: float4 f -> krow f/(BN/4), col (f%(BN/4))*4
#pragma unroll
        for (int f = tid; f < B_F4; f += 256) {
            int kr = f / (BN / 4), nq = (f % (BN / 4)) * 4;
            *(float4*)(&Bs[kr][nq]) = *(const float4*)(B + (size_t)(k0 + kr) * Nc + bn + nq);
        }
        __syncthreads();
#pragma unroll
        for (int k = 0; k < 16; ++k) {
            float a[TM], b[TN];
            *(float4*)(&a[0]) = *(const float4*)(&AsT[k][ty * 4]);
            if (TM == 8) *(float4*)(&a[4]) = *(const float4*)(&AsT[k][64 + ty * 4]);
            *(float4*)(&b[0]) = *(const float4*)(&Bs[k][tx * 4]);
            if (TN == 8) *(float4*)(&b[4]) = *(const float4*)(&Bs[k][64 + tx * 4]);
#pragma unroll
            for (int i = 0; i < TM; ++i)
#pragma unroll
                for (int j = 0; j < TN; ++j)
                    acc[i][j] += a[i] * b[j];
        }
        __syncthreads();
    }
#pragma unroll
    for (int i = 0; i < TM; ++i) {
        int m = bm + ((i < 4) ? (ty * 4 + i) : (64 + ty * 4 + i - 4));
        if (m < M) {
#pragma unroll
            for (int jq = 0; jq < TN; jq += 4) {
                int c0 = bn + ((jq == 0) ? tx * 4 : 64 + tx * 4);
                float4 o = make_float4(acc[i][jq], acc[i][jq + 1], acc[i][jq + 2], acc[i][jq + 3]);
                *(float4*)(C + (size_t)m * Nc + c0) = o;
            }
        }
    }
}

// ---------------- attention scalar products, layer 1: a_src/a_dst [N,4] ----------------
__global__ __launch_bounds__(256) void att1_kernel(const float* __restrict__ h1,
                                                   const float* __restrict__ att_src,
                                                   const float* __restrict__ att_dst,
                                                   float* __restrict__ a_src,
                                                   float* __restrict__ a_dst)
{
    const int wave = threadIdx.x >> 6, lane = threadIdx.x & 63;
    const int n = blockIdx.x * 4 + wave;
    if (n >= N_NODES) return;
    const int h = lane >> 4;
    float4 v = *(const float4*)(h1 + (size_t)n * D1 + lane * 4);
    float4 s4 = *(const float4*)(att_src + lane * 4);
    float4 d4 = *(const float4*)(att_dst + lane * 4);
    float ps = v.x * s4.x + v.y * s4.y + v.z * s4.z + v.w * s4.w;
    float pd = v.x * d4.x + v.y * d4.y + v.z * d4.z + v.w * d4.w;
#pragma unroll
    for (int o = 1; o < 16; o <<= 1) { ps += __shfl_xor(ps, o); pd += __shfl_xor(pd, o); }
    if ((lane & 15) == 0) { a_src[n * 4 + h] = ps; a_dst[n * 4 + h] = pd; }
}

// ---------------- attention scalar products, layer 2: a_src/a_dst [N] ----------------
__global__ __launch_bounds__(256) void att2_kernel(const float* __restrict__ h2,
                                                   const float* __restrict__ att_src,
                                                   const float* __restrict__ att_dst,
                                                   float* __restrict__ a_src,
                                                   float* __restrict__ a_dst)
{
    const int wave = threadIdx.x >> 6, lane = threadIdx.x & 63;
    const int n = blockIdx.x * 4 + wave;
    if (n >= N_NODES) return;
    float v = h2[(size_t)n * HID + lane];
    float ps = v * att_src[lane];
    float pd = v * att_dst[lane];
#pragma unroll
    for (int o = 1; o < 64; o <<= 1) { ps += __shfl_xor(ps, o); pd += __shfl_xor(pd, o); }
    if (lane == 0) { a_src[n] = ps; a_dst[n] = pd; }
}

// ---------------- CSR build: histogram, scan, scatter ----------------
__global__ void edge_hist(const int* __restrict__ ei, int* __restrict__ deg)
{
    for (int e = blockIdx.x * blockDim.x + threadIdx.x; e < E_TOT; e += gridDim.x * blockDim.x) {
        int d = (e < E_EDGES) ? ei[E_EDGES + e] : (e - E_EDGES);
        atomicAdd(&deg[d], 1);
    }
}

__global__ __launch_bounds__(SCAN_B) void scan_block(const int* __restrict__ deg,
                                                     int* __restrict__ incl,
                                                     int* __restrict__ bsum, int n)
{
    __shared__ int s[SCAN_B];
    int i = blockIdx.x * SCAN_B + threadIdx.x;
    int v = (i < n) ? deg[i] : 0;
    s[threadIdx.x] = v;
    __syncthreads();
    for (int off = 1; off < SCAN_B; off <<= 1) {
        int t = (threadIdx.x >= off) ? s[threadIdx.x - off] : 0;
        __syncthreads();
        s[threadIdx.x] += t;
        __syncthreads();
    }
    if (i < n) incl[i] = s[threadIdx.x];
    if (threadIdx.x == SCAN_B - 1) bsum[blockIdx.x] = s[SCAN_B - 1];
}

__global__ void scan_bsum(const int* __restrict__ bsum, int* __restrict__ bex, int nb)
{
    if (threadIdx.x == 0 && blockIdx.x == 0) {
        int run = 0;
        for (int b = 0; b < nb; ++b) { bex[b] = run; run += bsum[b]; }
    }
}

__global__ void finalize_off(const int* __restrict__ deg, const int* __restrict__ incl,
                             const int* __restrict__ bex, int* __restrict__ off,
                             int* __restrict__ cursor, int n)
{
    int i = blockIdx.x * blockDim.x + threadIdx.x;
    if (i < n) { off[i] = incl[i] - deg[i] + bex[i / SCAN_B]; cursor[i] = 0; }
}

__global__ void edge_scatter(const int* __restrict__ ei, const int* __restrict__ off,
                             int* __restrict__ cursor, int* __restrict__ csr_src)
{
    for (int e = blockIdx.x * blockDim.x + threadIdx.x; e < E_TOT; e += gridDim.x * blockDim.x) {
        int s = (e < E_EDGES) ? ei[e] : (e - E_EDGES);
        int d = (e < E_EDGES) ? ei[E_EDGES + e] : (e - E_EDGES);
        int slot = off[d] + atomicAdd(&cursor[d], 1);
        csr_src[slot] = s;
    }
}

// ---------------- layer-1 aggregation: wave per node, 2-deep software pipeline ----------------
__global__ __launch_bounds__(256) void agg1_kernel(const float* __restrict__ h1,
                                                   const int* __restrict__ csr_src,
                                                   const int* __restrict__ off,
                                                   const int* __restrict__ deg,
                                                   const float* __restrict__ a_src,
                                                   const float* __restrict__ a_dst,
                                                   const float* __restrict__ b1,
                                                   float* __restrict__ hE)
{
    const int wave = threadIdx.x >> 6, lane = threadIdx.x & 63;
    const int n = blockIdx.x * 4 + wave;
    if (n >= N_NODES) return;
    const int h = lane >> 4;
    const float adn = a_dst[n * 4 + h];
    const int st = off[n], cnt = deg[n];
    float4 acc = make_float4(0.f, 0.f, 0.f, 0.f);
    float dsum = 0.f;

    int s_cur = csr_src[st];                           // deg >= 1 (self-loop)
    int s_nxt = (cnt > 1) ? csr_src[st + 1] : s_cur;
    float a_cur = a_src[s_cur * 4 + h];
    float4 v_cur = *(const float4*)(h1 + (size_t)s_cur * D1 + lane * 4);

    for (int j = 0; j < cnt; ++j) {
        // issue loads for j+1 (data) and j+2 (index) before consuming j
        float a_nxt = a_src[s_nxt * 4 + h];
        float4 v_nxt = *(const float4*)(h1 + (size_t)s_nxt * D1 + lane * 4);
        int s_n2 = (j + 2 < cnt) ? csr_src[st + j + 2] : s_nxt;

        float al = a_cur + adn;
        al = (al > 0.f) ? al : NEG_SLOPE * al;
        float ex = __expf(al);
        dsum += ex;
        acc.x += ex * v_cur.x; acc.y += ex * v_cur.y;
        acc.z += ex * v_cur.z; acc.w += ex * v_cur.w;

        a_cur = a_nxt; v_cur = v_nxt; s_nxt = s_n2;
    }
    const float inv = 1.f / (dsum + 1e-16f);
    float4 bb = *(const float4*)(b1 + lane * 4);
    float4 o;
    o.x = acc.x * inv + bb.x;
    o.y = acc.y * inv + bb.y;
    o.z = acc.z * inv + bb.z;
    o.w = acc.w * inv + bb.w;
    o.x = (o.x > 0.f) ? o.x : expm1f(o.x);
    o.y = (o.y > 0.f) ? o.y : expm1f(o.y);
    o.z = (o.z > 0.f) ? o.z : expm1f(o.z);
    o.w = (o.w > 0.f) ? o.w : expm1f(o.w);
    *(float4*)(hE + (size_t)n * D1 + lane * 4) = o;
}

// ---------------- layer-2 aggregation + register-accumulated mean-pool ----------------
__global__ __launch_bounds__(256) void agg2_pool_kernel(const float* __restrict__ h2,
                                                        const int* __restrict__ csr_src,
                                                        const int* __restrict__ off,
                                                        const int* __restrict__ deg,
                                                        const float* __restrict__ a_src,
                                                        const float* __restrict__ a_dst,
                                                        const float* __restrict__ b2,
                                                        const int* __restrict__ batch,
                                                        float* __restrict__ pool,
                                                        float* __restrict__ cntg)
{
    const int wave = threadIdx.x >> 6, lane = threadIdx.x & 63;
    const int wgid = blockIdx.x * 4 + wave;
    const int n0 = wgid * CHUNK2;
    if (n0 >= N_NODES) return;
    const int n1 = (n0 + CHUNK2 < N_NODES) ? n0 + CHUNK2 : N_NODES;
    const float bb = b2[lane];

    float poolacc = 0.f, ccur = 0.f;
    int gcur = batch[n0];

    for (int n = n0; n < n1; ++n) {
        const float adn = a_dst[n];
        const int st = off[n], cnt = deg[n];
        float acc = 0.f, dsum = 0.f;

        int s_cur = csr_src[st];
        int s_nxt = (cnt > 1) ? csr_src[st + 1] : s_cur;
        float a_cur = a_src[s_cur];
        float v_cur = h2[(size_t)s_cur * HID + lane];

        for (int j = 0; j < cnt; ++j) {
            float a_nxt = a_src[s_nxt];
            float v_nxt = h2[(size_t)s_nxt * HID + lane];
            int s_n2 = (j + 2 < cnt) ? csr_src[st + j + 2] : s_nxt;

            float al = a_cur + adn;
            al = (al > 0.f) ? al : NEG_SLOPE * al;
            float ex = __expf(al);
            dsum += ex;
            acc += ex * v_cur;

            a_cur = a_nxt; v_cur = v_nxt; s_nxt = s_n2;
        }
        float val = acc / (dsum + 1e-16f) + bb;
        int g = batch[n];
        if (g != gcur) {
#if defined(__AMDGCN__)
            unsafeAtomicAdd(&pool[gcur * HID + lane], poolacc);
            if (lane == 0) unsafeAtomicAdd(&cntg[gcur], ccur);
#else
            atomicAdd(&pool[gcur * HID + lane], poolacc);
            if (lane == 0) atomicAdd(&cntg[gcur], ccur);
#endif
            poolacc = 0.f; ccur = 0.f; gcur = g;
        }
        poolacc += val;
        ccur += 1.f;
    }
#if defined(__AMDGCN__)
    unsafeAtomicAdd(&pool[gcur * HID + lane], poolacc);
    if (lane == 0) unsafeAtomicAdd(&cntg[gcur], ccur);
#else
    atomicAdd(&pool[gcur * HID + lane], poolacc);
    if (lane == 0) atomicAdd(&cntg[gcur], ccur);
#endif
}

// ---------------- head: mean, relu MLP, logits ----------------
__global__ void head_kernel(const float* __restrict__ pool, const float* __restrict__ cntg,
                            const float* __restrict__ W3, const float* __restrict__ b3,
                            const float* __restrict__ W4, const float* __restrict__ b4,
                            float* __restrict__ out)
{
    int g = threadIdx.x;
    if (g >= G_GRAPHS) return;
    float invc = 1.f / fmaxf(cntg[g], 1.f);
    float emb[HID];
#pragma unroll
    for (int k = 0; k < HID; ++k) emb[k] = pool[g * HID + k] * invc;
    float z[32];
    for (int j = 0; j < 32; ++j) {
        float s = b3[j];
        for (int k = 0; k < HID; ++k) s += emb[k] * W3[k * 32 + j];
        z[j] = fmaxf(s, 0.f);
    }
    for (int d = 0; d < 2; ++d) {
        float s = b4[d];
        for (int j = 0; j < 32; ++j) s += z[j] * W4[j * 2 + d];
        out[g * 2 + d] = s;
    }
}

extern "C" void kernel_launch(void* const* d_in, const int* in_sizes, int n_in,
                              void* d_out, int out_size, void* d_ws, size_t ws_size,
                              hipStream_t stream)
{
    const float* x     = (const float*)d_in[0];
    const int*   ei    = (const int*)d_in[1];
    const int*   batch = (const int*)d_in[2];
    const float* W1    = (const float*)d_in[3];
    const float* as1w  = (const float*)d_in[4];
    const float* ad1w  = (const float*)d_in[5];
    const float* b1    = (const float*)d_in[6];
    const float* W2    = (const float*)d_in[7];
    const float* as2w  = (const float*)d_in[8];
    const float* ad2w  = (const float*)d_in[9];
    const float* b2    = (const float*)d_in[10];
    const float* W3    = (const float*)d_in[11];
    const float* b3    = (const float*)d_in[12];
    const float* W4    = (const float*)d_in[13];
    const float* b4    = (const float*)d_in[14];
    float* out = (float*)d_out;

    char* ws = (char*)d_ws;
    size_t o = 0;
    auto alloc = [&](size_t bytes) -> void* {
        void* p = ws + o;
        o += (bytes + 255) & ~(size_t)255;
        return p;
    };
    float* h1   = (float*)alloc((size_t)N_NODES * D1 * 4);
    float* hE   = (float*)alloc((size_t)N_NODES * D1 * 4);
    float* h2   = h1;                                        // alias: h1 dead after agg1
    float* a_s1 = (float*)alloc((size_t)N_NODES * 4 * 4);
    float* a_d1 = (float*)alloc((size_t)N_NODES * 4 * 4);
    float* a_s2 = (float*)alloc((size_t)N_NODES * 4);
    float* a_d2 = (float*)alloc((size_t)N_NODES * 4);
    int*   deg    = (int*)alloc((size_t)N_NODES * 4);
    int*   incl   = (int*)alloc((size_t)N_NODES * 4);
    int*   offv   = (int*)alloc((size_t)N_NODES * 4);
    int*   cursor = (int*)alloc((size_t)N_NODES * 4);
    int*   bsum   = (int*)alloc(128 * 4);
    int*   bex    = (int*)alloc(128 * 4);
    int*   csr    = (int*)alloc((size_t)E_TOT * 4);
    float* pool   = (float*)alloc((size_t)G_GRAPHS * HID * 4);
    float* cntg   = (float*)alloc((size_t)G_GRAPHS * 4);

    hipMemsetAsync(deg, 0, (size_t)N_NODES * 4, stream);
    hipMemsetAsync(pool, 0, (size_t)G_GRAPHS * HID * 4, stream);
    hipMemsetAsync(cntg, 0, (size_t)G_GRAPHS * 4, stream);

    const int nblk_nodes = (N_NODES + 3) / 4;
    const int nscan = (N_NODES + SCAN_B - 1) / SCAN_B;

    // GEMM1: h1 = x @ W1  [100000,256]x[256,256], 128x128 tile
    gemm_tiled<128, 128, 8, 8><<<dim3(D1 / 128, (N_NODES + 127) / 128), 256, 0, stream>>>(x, W1, h1, N_NODES, IN_DIM, D1);
    att1_kernel<<<nblk_nodes, 256, 0, stream>>>(h1, as1w, ad1w, a_s1, a_d1);

    // CSR build (shared by both layers)
    edge_hist<<<4096, 256, 0, stream>>>(ei, deg);
    scan_block<<<nscan, SCAN_B, 0, stream>>>(deg, incl, bsum, N_NODES);
    scan_bsum<<<1, 64, 0, stream>>>(bsum, bex, nscan);
    finalize_off<<<(N_NODES + 255) / 256, 256, 0, stream>>>(deg, incl, bex, offv, cursor, N_NODES);
    edge_scatter<<<4096, 256, 0, stream>>>(ei, offv, cursor, csr);

    // layer-1 gather-aggregate, fused softmax + b1 + ELU
    agg1_kernel<<<nblk_nodes, 256, 0, stream>>>(h1, csr, offv, deg, a_s1, a_d1, b1, hE);

    // GEMM2: h2 = hE @ W2  [100000,256]x[256,64], 128x64 tile
    gemm_tiled<128, 64, 8, 4><<<dim3(1, (N_NODES + 127) / 128), 256, 0, stream>>>(hE, W2, h2, N_NODES, D1, HID);
    att2_kernel<<<nblk_nodes, 256, 0, stream>>>(h2, as2w, ad2w, a_s2, a_d2);

    // layer-2 gather-aggregate + register-accumulated mean-pool
    const int nwaves2 = (N_NODES + CHUNK2 - 1) / CHUNK2;
    agg2_pool_kernel<<<(nwaves2 + 3) / 4, 256, 0, stream>>>(h2, csr, offv, deg, a_s2, a_d2, b2, batch, pool, cntg);

    // head MLP
    head_kernel<<<1, 64, 0, stream>>>(pool, cntg, W3, b3, W4, b4, out);
}

// Round 5
// 1079.095 us; speedup vs baseline: 1.0406x; 1.0406x over previous
//
#include <hip/hip_runtime.h>
#include <math.h>

#define N_NODES 100000
#define E_EDGES 1600000
#define E_TOT   (E_EDGES + N_NODES)
#define G_GRAPHS 64
#define IN_DIM 256
#define HID 64
#define HEADS 4
#define D1 256            // HEADS*HID
#define NEG_SLOPE 0.2f
#define SCAN_B 1024
#define CHUNK2 8          // nodes per wave in agg2

typedef float nfloat4 __attribute__((ext_vector_type(4)));   // native vec for nontemporal builtins

// ---------------- generic fp32 tiled GEMM: C[M,Nc] = A[M,K] @ B[K,Nc] ----------------
// tile 64x64x16, 256 threads, 4x4 microtile  (round-2-proven config)
__global__ __launch_bounds__(256) void gemm_tiled(const float* __restrict__ A,
                                                  const float* __restrict__ B,
                                                  float* __restrict__ C,
                                                  int M, int K, int Nc)
{
    __shared__ float AsT[16][68];   // [k][m]
    __shared__ float Bs[16][68];    // [k][n]
    const int tid = threadIdx.x;
    const int tx = tid & 15, ty = tid >> 4;
    const int bm = blockIdx.y * 64, bn = blockIdx.x * 64;
    float acc[4][4] = {};

    const int ar  = tid >> 2;          // 0..63 : A row within tile
    const int akq = (tid & 3) * 4;     // 0,4,8,12 : k quad
    const int bkr = tid >> 4;          // 0..15 : B k row
    const int bnq = (tid & 15) * 4;    // 0..60 : B col quad

    for (int k0 = 0; k0 < K; k0 += 16) {
        float4 av = make_float4(0.f, 0.f, 0.f, 0.f);
        int m = bm + ar;
        if (m < M) av = *(const float4*)(A + (size_t)m * K + k0 + akq);
        AsT[akq + 0][ar] = av.x;
        AsT[akq + 1][ar] = av.y;
        AsT[akq + 2][ar] = av.z;
        AsT[akq + 3][ar] = av.w;
        float4 bv = *(const float4*)(B + (size_t)(k0 + bkr) * Nc + bn + bnq);
        *(float4*)(&Bs[bkr][bnq]) = bv;
        __syncthreads();
#pragma unroll
        for (int k = 0; k < 16; ++k) {
            float4 a4 = *(const float4*)(&AsT[k][ty * 4]);
            float4 b4 = *(const float4*)(&Bs[k][tx * 4]);
            acc[0][0] += a4.x * b4.x; acc[0][1] += a4.x * b4.y; acc[0][2] += a4.x * b4.z; acc[0][3] += a4.x * b4.w;
            acc[1][0] += a4.y * b4.x; acc[1][1] += a4.y * b4.y; acc[1][2] += a4.y * b4.z; acc[1][3] += a4.y * b4.w;
            acc[2][0] += a4.z * b4.x; acc[2][1] += a4.z * b4.y; acc[2][2] += a4.z * b4.z; acc[2][3] += a4.z * b4.w;
            acc[3][0] += a4.w * b4.x; acc[3][1] += a4.w * b4.y; acc[3][2] += a4.w * b4.z; acc[3][3] += a4.w * b4.w;
        }
        __syncthreads();
    }
#pragma unroll
    for (int i = 0; i < 4; ++i) {
        int m = bm + ty * 4 + i;
        if (m < M) {
#pragma unroll
            for (int j = 0; j < 4; ++j)
                C[(size_t)m * Nc + bn + tx * 4 + j] = acc[i][j];
        }
    }
}

// ---------------- attention scalar products, layer 1: a_src/a_dst [N,4] ----------------
__global__ __launch_bounds__(256) void att1_kernel(const float* __restrict__ h1,
                                                   const float* __restrict__ att_src,
                                                   const float* __restrict__ att_dst,
                                                   float* __restrict__ a_src,
                                                   float* __restrict__ a_dst)
{
    const int wave = threadIdx.x >> 6, lane = threadIdx.x & 63;
    const int n = blockIdx.x * 4 + wave;
    if (n >= N_NODES) return;
    const int h = lane >> 4;
    float4 v = *(const float4*)(h1 + (size_t)n * D1 + lane * 4);
    float4 s4 = *(const float4*)(att_src + lane * 4);
    float4 d4 = *(const float4*)(att_dst + lane * 4);
    float ps = v.x * s4.x + v.y * s4.y + v.z * s4.z + v.w * s4.w;
    float pd = v.x * d4.x + v.y * d4.y + v.z * d4.z + v.w * d4.w;
#pragma unroll
    for (int o = 1; o < 16; o <<= 1) { ps += __shfl_xor(ps, o); pd += __shfl_xor(pd, o); }
    if ((lane & 15) == 0) { a_src[n * 4 + h] = ps; a_dst[n * 4 + h] = pd; }
}

// ---------------- attention scalar products, layer 2: a_src/a_dst [N] ----------------
__global__ __launch_bounds__(256) void att2_kernel(const float* __restrict__ h2,
                                                   const float* __restrict__ att_src,
                                                   const float* __restrict__ att_dst,
                                                   float* __restrict__ a_src,
                                                   float* __restrict__ a_dst)
{
    const int wave = threadIdx.x >> 6, lane = threadIdx.x & 63;
    const int n = blockIdx.x * 4 + wave;
    if (n >= N_NODES) return;
    float v = h2[(size_t)n * HID + lane];
    float ps = v * att_src[lane];
    float pd = v * att_dst[lane];
#pragma unroll
    for (int o = 1; o < 64; o <<= 1) { ps += __shfl_xor(ps, o); pd += __shfl_xor(pd, o); }
    if (lane == 0) { a_src[n] = ps; a_dst[n] = pd; }
}

// ---------------- CSR build: histogram, scan, scatter ----------------
__global__ void edge_hist(const int* __restrict__ ei, int* __restrict__ deg)
{
    for (int e = blockIdx.x * blockDim.x + threadIdx.x; e < E_TOT; e += gridDim.x * blockDim.x) {
        int d = (e < E_EDGES) ? ei[E_EDGES + e] : (e - E_EDGES);
        atomicAdd(&deg[d], 1);
    }
}

__global__ __launch_bounds__(SCAN_B) void scan_block(const int* __restrict__ deg,
                                                     int* __restrict__ incl,
                                                     int* __restrict__ bsum, int n)
{
    __shared__ int s[SCAN_B];
    int i = blockIdx.x * SCAN_B + threadIdx.x;
    int v = (i < n) ? deg[i] : 0;
    s[threadIdx.x] = v;
    __syncthreads();
    for (int off = 1; off < SCAN_B; off <<= 1) {
        int t = (threadIdx.x >= off) ? s[threadIdx.x - off] : 0;
        __syncthreads();
        s[threadIdx.x] += t;
        __syncthreads();
    }
    if (i < n) incl[i] = s[threadIdx.x];
    if (threadIdx.x == SCAN_B - 1) bsum[blockIdx.x] = s[SCAN_B - 1];
}

__global__ void scan_bsum(const int* __restrict__ bsum, int* __restrict__ bex, int nb)
{
    if (threadIdx.x == 0 && blockIdx.x == 0) {
        int run = 0;
        for (int b = 0; b < nb; ++b) { bex[b] = run; run += bsum[b]; }
    }
}

__global__ void finalize_off(const int* __restrict__ deg, const int* __restrict__ incl,
                             const int* __restrict__ bex, int* __restrict__ off,
                             int* __restrict__ cursor, int n)
{
    int i = blockIdx.x * blockDim.x + threadIdx.x;
    if (i < n) { off[i] = incl[i] - deg[i] + bex[i / SCAN_B]; cursor[i] = 0; }
}

__global__ void edge_scatter(const int* __restrict__ ei, const int* __restrict__ off,
                             int* __restrict__ cursor, int* __restrict__ csr_src)
{
    for (int e = blockIdx.x * blockDim.x + threadIdx.x; e < E_TOT; e += gridDim.x * blockDim.x) {
        int s = (e < E_EDGES) ? ei[e] : (e - E_EDGES);
        int d = (e < E_EDGES) ? ei[E_EDGES + e] : (e - E_EDGES);
        int slot = off[d] + atomicAdd(&cursor[d], 1);
        csr_src[slot] = s;
    }
}

// ---------------- layer-1 aggregation: wave per node ----------------
// hE stored NON-TEMPORALLY: the 100 MB output stream must not evict the
// LLC-resident h1 (100 MB) that the random gathers re-read ~17x.
__global__ __launch_bounds__(256) void agg1_kernel(const float* __restrict__ h1,
                                                   const int* __restrict__ csr_src,
                                                   const int* __restrict__ off,
                                                   const int* __restrict__ deg,
                                                   const float* __restrict__ a_src,
                                                   const float* __restrict__ a_dst,
                                                   const float* __restrict__ b1,
                                                   float* __restrict__ hE)
{
    const int wave = threadIdx.x >> 6, lane = threadIdx.x & 63;
    const int n = blockIdx.x * 4 + wave;
    if (n >= N_NODES) return;
    const int h = lane >> 4;
    const float adn = a_dst[n * 4 + h];
    const int st = off[n], cnt = deg[n];
    float4 acc = make_float4(0.f, 0.f, 0.f, 0.f);
    float dsum = 0.f;

    int s_cur = csr_src[st];                           // deg >= 1 (self-loop)
    int s_nxt = (cnt > 1) ? csr_src[st + 1] : s_cur;
    float a_cur = a_src[s_cur * 4 + h];
    float4 v_cur = *(const float4*)(h1 + (size_t)s_cur * D1 + lane * 4);

    for (int j = 0; j < cnt; ++j) {
        float a_nxt = a_src[s_nxt * 4 + h];
        float4 v_nxt = *(const float4*)(h1 + (size_t)s_nxt * D1 + lane * 4);
        int s_n2 = (j + 2 < cnt) ? csr_src[st + j + 2] : s_nxt;

        float al = a_cur + adn;
        al = (al > 0.f) ? al : NEG_SLOPE * al;
        float ex = __expf(al);
        dsum += ex;
        acc.x += ex * v_cur.x; acc.y += ex * v_cur.y;
        acc.z += ex * v_cur.z; acc.w += ex * v_cur.w;

        a_cur = a_nxt; v_cur = v_nxt; s_nxt = s_n2;
    }
    const float inv = 1.f / (dsum + 1e-16f);
    float4 bb = *(const float4*)(b1 + lane * 4);
    nfloat4 o;
    o.x = acc.x * inv + bb.x;
    o.y = acc.y * inv + bb.y;
    o.z = acc.z * inv + bb.z;
    o.w = acc.w * inv + bb.w;
    o.x = (o.x > 0.f) ? o.x : expm1f(o.x);
    o.y = (o.y > 0.f) ? o.y : expm1f(o.y);
    o.z = (o.z > 0.f) ? o.z : expm1f(o.z);
    o.w = (o.w > 0.f) ? o.w : expm1f(o.w);
    __builtin_nontemporal_store(o, (nfloat4*)(hE + (size_t)n * D1 + lane * 4));
}

// ---------------- layer-2 aggregation + register-accumulated mean-pool ----------------
__global__ __launch_bounds__(256) void agg2_pool_kernel(const float* __restrict__ h2,
                                                        const int* __restrict__ csr_src,
                                                        const int* __restrict__ off,
                                                        const int* __restrict__ deg,
                                                        const float* __restrict__ a_src,
                                                        const float* __restrict__ a_dst,
                                                        const float* __restrict__ b2,
                                                        const int* __restrict__ batch,
                                                        float* __restrict__ pool,
                                                        float* __restrict__ cntg)
{
    const int wave = threadIdx.x >> 6, lane = threadIdx.x & 63;
    const int wgid = blockIdx.x * 4 + wave;
    const int n0 = wgid * CHUNK2;
    if (n0 >= N_NODES) return;
    const int n1 = (n0 + CHUNK2 < N_NODES) ? n0 + CHUNK2 : N_NODES;
    const float bb = b2[lane];

    float poolacc = 0.f, ccur = 0.f;
    int gcur = batch[n0];

    for (int n = n0; n < n1; ++n) {
        const float adn = a_dst[n];
        const int st = off[n], cnt = deg[n];
        float acc = 0.f, dsum = 0.f;

        int s_cur = csr_src[st];
        int s_nxt = (cnt > 1) ? csr_src[st + 1] : s_cur;
        float a_cur = a_src[s_cur];
        float v_cur = h2[(size_t)s_cur * HID + lane];

        for (int j = 0; j < cnt; ++j) {
            float a_nxt = a_src[s_nxt];
            float v_nxt = h2[(size_t)s_nxt * HID + lane];
            int s_n2 = (j + 2 < cnt) ? csr_src[st + j + 2] : s_nxt;

            float al = a_cur + adn;
            al = (al > 0.f) ? al : NEG_SLOPE * al;
            float ex = __expf(al);
            dsum += ex;
            acc += ex * v_cur;

            a_cur = a_nxt; v_cur = v_nxt; s_nxt = s_n2;
        }
        float val = acc / (dsum + 1e-16f) + bb;
        int g = batch[n];
        if (g != gcur) {
#if defined(__AMDGCN__)
            unsafeAtomicAdd(&pool[gcur * HID + lane], poolacc);
            if (lane == 0) unsafeAtomicAdd(&cntg[gcur], ccur);
#else
            atomicAdd(&pool[gcur * HID + lane], poolacc);
            if (lane == 0) atomicAdd(&cntg[gcur], ccur);
#endif
            poolacc = 0.f; ccur = 0.f; gcur = g;
        }
        poolacc += val;
        ccur += 1.f;
    }
#if defined(__AMDGCN__)
    unsafeAtomicAdd(&pool[gcur * HID + lane], poolacc);
    if (lane == 0) unsafeAtomicAdd(&cntg[gcur], ccur);
#else
    atomicAdd(&pool[gcur * HID + lane], poolacc);
    if (lane == 0) atomicAdd(&cntg[gcur], ccur);
#endif
}

// ---------------- head: mean, relu MLP, logits ----------------
__global__ void head_kernel(const float* __restrict__ pool, const float* __restrict__ cntg,
                            const float* __restrict__ W3, const float* __restrict__ b3,
                            const float* __restrict__ W4, const float* __restrict__ b4,
                            float* __restrict__ out)
{
    int g = threadIdx.x;
    if (g >= G_GRAPHS) return;
    float invc = 1.f / fmaxf(cntg[g], 1.f);
    float emb[HID];
#pragma unroll
    for (int k = 0; k < HID; ++k) emb[k] = pool[g * HID + k] * invc;
    float z[32];
    for (int j = 0; j < 32; ++j) {
        float s = b3[j];
        for (int k = 0; k < HID; ++k) s += emb[k] * W3[k * 32 + j];
        z[j] = fmaxf(s, 0.f);
    }
    for (int d = 0; d < 2; ++d) {
        float s = b4[d];
        for (int j = 0; j < 32; ++j) s += z[j] * W4[j * 2 + d];
        out[g * 2 + d] = s;
    }
}

extern "C" void kernel_launch(void* const* d_in, const int* in_sizes, int n_in,
                              void* d_out, int out_size, void* d_ws, size_t ws_size,
                              hipStream_t stream)
{
    const float* x     = (const float*)d_in[0];
    const int*   ei    = (const int*)d_in[1];
    const int*   batch = (const int*)d_in[2];
    const float* W1    = (const float*)d_in[3];
    const float* as1w  = (const float*)d_in[4];
    const float* ad1w  = (const float*)d_in[5];
    const float* b1    = (const float*)d_in[6];
    const float* W2    = (const float*)d_in[7];
    const float* as2w  = (const float*)d_in[8];
    const float* ad2w  = (const float*)d_in[9];
    const float* b2    = (const float*)d_in[10];
    const float* W3    = (const float*)d_in[11];
    const float* b3    = (const float*)d_in[12];
    const float* W4    = (const float*)d_in[13];
    const float* b4    = (const float*)d_in[14];
    float* out = (float*)d_out;

    char* ws = (char*)d_ws;
    size_t o = 0;
    auto alloc = [&](size_t bytes) -> void* {
        void* p = ws + o;
        o += (bytes + 255) & ~(size_t)255;
        return p;
    };
    float* h1   = (float*)alloc((size_t)N_NODES * D1 * 4);
    float* hE   = (float*)alloc((size_t)N_NODES * D1 * 4);
    float* h2   = h1;                                        // alias: h1 dead after agg1
    float* a_s1 = (float*)alloc((size_t)N_NODES * 4 * 4);
    float* a_d1 = (float*)alloc((size_t)N_NODES * 4 * 4);
    float* a_s2 = (float*)alloc((size_t)N_NODES * 4);
    float* a_d2 = (float*)alloc((size_t)N_NODES * 4);
    int*   deg    = (int*)alloc((size_t)N_NODES * 4);
    int*   incl   = (int*)alloc((size_t)N_NODES * 4);
    int*   offv   = (int*)alloc((size_t)N_NODES * 4);
    int*   cursor = (int*)alloc((size_t)N_NODES * 4);
    int*   bsum   = (int*)alloc(128 * 4);
    int*   bex    = (int*)alloc(128 * 4);
    int*   csr    = (int*)alloc((size_t)E_TOT * 4);
    float* pool   = (float*)alloc((size_t)G_GRAPHS * HID * 4);
    float* cntg   = (float*)alloc((size_t)G_GRAPHS * 4);

    (void)hipMemsetAsync(deg, 0, (size_t)N_NODES * 4, stream);
    (void)hipMemsetAsync(pool, 0, (size_t)G_GRAPHS * HID * 4, stream);
    (void)hipMemsetAsync(cntg, 0, (size_t)G_GRAPHS * 4, stream);

    const int nblk_nodes = (N_NODES + 3) / 4;
    const int nscan = (N_NODES + SCAN_B - 1) / SCAN_B;

    // GEMM1: h1 = x @ W1  [100000,256]x[256,256]
    gemm_tiled<<<dim3(D1 / 64, (N_NODES + 63) / 64), 256, 0, stream>>>(x, W1, h1, N_NODES, IN_DIM, D1);
    att1_kernel<<<nblk_nodes, 256, 0, stream>>>(h1, as1w, ad1w, a_s1, a_d1);

    // CSR build (shared by both layers)
    edge_hist<<<4096, 256, 0, stream>>>(ei, deg);
    scan_block<<<nscan, SCAN_B, 0, stream>>>(deg, incl, bsum, N_NODES);
    scan_bsum<<<1, 64, 0, stream>>>(bsum, bex, nscan);
    finalize_off<<<(N_NODES + 255) / 256, 256, 0, stream>>>(deg, incl, bex, offv, cursor, N_NODES);
    edge_scatter<<<4096, 256, 0, stream>>>(ei, offv, cursor, csr);

    // layer-1 gather-aggregate, fused softmax + b1 + ELU (nontemporal hE store)
    agg1_kernel<<<nblk_nodes, 256, 0, stream>>>(h1, csr, offv, deg, a_s1, a_d1, b1, hE);

    // GEMM2: h2 = hE @ W2  [100000,256]x[256,64]
    gemm_tiled<<<dim3(HID / 64, (N_NODES + 63) / 64), 256, 0, stream>>>(hE, W2, h2, N_NODES, D1, HID);
    att2_kernel<<<nblk_nodes, 256, 0, stream>>>(h2, as2w, ad2w, a_s2, a_d2);

    // layer-2 gather-aggregate + register-accumulated mean-pool
    const int nwaves2 = (N_NODES + CHUNK2 - 1) / CHUNK2;
    agg2_pool_kernel<<<(nwaves2 + 3) / 4, 256, 0, stream>>>(h2, csr, offv, deg, a_s2, a_d2, b2, batch, pool, cntg);

    // head MLP
    head_kernel<<<1, 64, 0, stream>>>(pool, cntg, W3, b3, W4, b4, out);
}

// Round 6
// 1022.569 us; speedup vs baseline: 1.0982x; 1.0553x over previous
//
#include <hip/hip_runtime.h>
#include <math.h>

#define N_NODES 100000
#define E_EDGES 1600000
#define E_TOT   (E_EDGES + N_NODES)
#define G_GRAPHS 64
#define IN_DIM 256
#define HID 64
#define HEADS 4
#define D1 256            // HEADS*HID
#define NEG_SLOPE 0.2f
#define SCAN_B 1024
#define CHUNK2 16         // nodes per wave in agg2 (r2-proven)

typedef float nfloat4 __attribute__((ext_vector_type(4)));

// ---------------- GEMM1 + att1 fused ----------------
// h1 = x @ W1, tile 128x64, 256 thr, 8x4 microtile. blockIdx.x = head (4 col-tiles
// of 64 = one head each) -> attention dots computed in-epilogue via 16-lane shuffle.
__global__ __launch_bounds__(256) void gemm1_att1(const float* __restrict__ A,
                                                  const float* __restrict__ B,
                                                  float* __restrict__ C,
                                                  const float* __restrict__ att_src,
                                                  const float* __restrict__ att_dst,
                                                  float* __restrict__ a_srcO,
                                                  float* __restrict__ a_dstO)
{
    __shared__ float AsT[16][132];   // [k][m] 128 rows
    __shared__ float Bs[16][68];     // [k][n] 64 cols
    const int tid = threadIdx.x, tx = tid & 15, ty = tid >> 4;
    const int bm = blockIdx.y * 128, h = blockIdx.x, bn = h * 64;
    float acc[8][4] = {};

    for (int k0 = 0; k0 < IN_DIM; k0 += 16) {
        // A: 128 rows x 16 k = 512 float4, 2 per thread
#pragma unroll
        for (int t = 0; t < 2; ++t) {
            int f = tid + t * 256;
            int row = f >> 2, kq = (f & 3) * 4;
            int m = bm + row;
            float4 av = make_float4(0.f, 0.f, 0.f, 0.f);
            if (m < N_NODES) av = *(const float4*)(A + (size_t)m * IN_DIM + k0 + kq);
            AsT[kq + 0][row] = av.x;
            AsT[kq + 1][row] = av.y;
            AsT[kq + 2][row] = av.z;
            AsT[kq + 3][row] = av.w;
        }
        // B: 16 k x 64 cols = 256 float4, 1 per thread
        *(float4*)(&Bs[ty][tx * 4]) = *(const float4*)(B + (size_t)(k0 + ty) * D1 + bn + tx * 4);
        __syncthreads();
#pragma unroll
        for (int k = 0; k < 16; ++k) {
            float a[8], b[4];
            *(float4*)(&a[0]) = *(const float4*)(&AsT[k][ty * 4]);
            *(float4*)(&a[4]) = *(const float4*)(&AsT[k][64 + ty * 4]);
            *(float4*)(&b[0]) = *(const float4*)(&Bs[k][tx * 4]);
#pragma unroll
            for (int i = 0; i < 8; ++i)
#pragma unroll
                for (int j = 0; j < 4; ++j)
                    acc[i][j] += a[i] * b[j];
        }
        __syncthreads();
    }

    const float4 sv = *(const float4*)(att_src + h * 64 + tx * 4);
    const float4 dv = *(const float4*)(att_dst + h * 64 + tx * 4);
#pragma unroll
    for (int i = 0; i < 8; ++i) {
        int m = bm + ((i < 4) ? (ty * 4 + i) : (64 + ty * 4 + (i - 4)));
        float ps = acc[i][0] * sv.x + acc[i][1] * sv.y + acc[i][2] * sv.z + acc[i][3] * sv.w;
        float pd = acc[i][0] * dv.x + acc[i][1] * dv.y + acc[i][2] * dv.z + acc[i][3] * dv.w;
#pragma unroll
        for (int o = 1; o < 16; o <<= 1) { ps += __shfl_xor(ps, o); pd += __shfl_xor(pd, o); }
        if (m < N_NODES) {
            *(float4*)(C + (size_t)m * D1 + bn + tx * 4) =
                make_float4(acc[i][0], acc[i][1], acc[i][2], acc[i][3]);
            if (tx == 0) { a_srcO[m * 4 + h] = ps; a_dstO[m * 4 + h] = pd; }
        }
    }
}

// ---------------- GEMM2 + att2 fused ----------------
// h2 = hE @ W2, tile 64x64 (r2-proven 4x4 microtile), single col-tile = all HID
// features -> att2 dots in-epilogue.
__global__ __launch_bounds__(256) void gemm2_att2(const float* __restrict__ A,
                                                  const float* __restrict__ B,
                                                  float* __restrict__ C,
                                                  const float* __restrict__ att_src,
                                                  const float* __restrict__ att_dst,
                                                  float* __restrict__ a_srcO,
                                                  float* __restrict__ a_dstO)
{
    __shared__ float AsT[16][68];
    __shared__ float Bs[16][68];
    const int tid = threadIdx.x;
    const int tx = tid & 15, ty = tid >> 4;
    const int bm = blockIdx.y * 64;
    float acc[4][4] = {};

    const int ar  = tid >> 2;
    const int akq = (tid & 3) * 4;

    for (int k0 = 0; k0 < D1; k0 += 16) {
        float4 av = make_float4(0.f, 0.f, 0.f, 0.f);
        int m = bm + ar;
        if (m < N_NODES) av = *(const float4*)(A + (size_t)m * D1 + k0 + akq);
        AsT[akq + 0][ar] = av.x;
        AsT[akq + 1][ar] = av.y;
        AsT[akq + 2][ar] = av.z;
        AsT[akq + 3][ar] = av.w;
        *(float4*)(&Bs[ty][tx * 4]) = *(const float4*)(B + (size_t)(k0 + ty) * HID + tx * 4);
        __syncthreads();
#pragma unroll
        for (int k = 0; k < 16; ++k) {
            float4 a4 = *(const float4*)(&AsT[k][ty * 4]);
            float4 b4 = *(const float4*)(&Bs[k][tx * 4]);
            acc[0][0] += a4.x * b4.x; acc[0][1] += a4.x * b4.y; acc[0][2] += a4.x * b4.z; acc[0][3] += a4.x * b4.w;
            acc[1][0] += a4.y * b4.x; acc[1][1] += a4.y * b4.y; acc[1][2] += a4.y * b4.z; acc[1][3] += a4.y * b4.w;
            acc[2][0] += a4.z * b4.x; acc[2][1] += a4.z * b4.y; acc[2][2] += a4.z * b4.z; acc[2][3] += a4.z * b4.w;
            acc[3][0] += a4.w * b4.x; acc[3][1] += a4.w * b4.y; acc[3][2] += a4.w * b4.z; acc[3][3] += a4.w * b4.w;
        }
        __syncthreads();
    }

    const float4 sv = *(const float4*)(att_src + tx * 4);
    const float4 dv = *(const float4*)(att_dst + tx * 4);
#pragma unroll
    for (int i = 0; i < 4; ++i) {
        int m = bm + ty * 4 + i;
        float ps = acc[i][0] * sv.x + acc[i][1] * sv.y + acc[i][2] * sv.z + acc[i][3] * sv.w;
        float pd = acc[i][0] * dv.x + acc[i][1] * dv.y + acc[i][2] * dv.z + acc[i][3] * dv.w;
#pragma unroll
        for (int o = 1; o < 16; o <<= 1) { ps += __shfl_xor(ps, o); pd += __shfl_xor(pd, o); }
        if (m < N_NODES) {
            *(float4*)(C + (size_t)m * HID + tx * 4) =
                make_float4(acc[i][0], acc[i][1], acc[i][2], acc[i][3]);
            if (tx == 0) { a_srcO[m] = ps; a_dstO[m] = pd; }
        }
    }
}

// ---------------- CSR build: histogram, scan, scatter ----------------
__global__ void edge_hist(const int* __restrict__ ei, int* __restrict__ deg)
{
    for (int e = blockIdx.x * blockDim.x + threadIdx.x; e < E_TOT; e += gridDim.x * blockDim.x) {
        int d = (e < E_EDGES) ? ei[E_EDGES + e] : (e - E_EDGES);
        atomicAdd(&deg[d], 1);
    }
}

__global__ __launch_bounds__(SCAN_B) void scan_block(const int* __restrict__ deg,
                                                     int* __restrict__ incl,
                                                     int* __restrict__ bsum, int n)
{
    __shared__ int s[SCAN_B];
    int i = blockIdx.x * SCAN_B + threadIdx.x;
    int v = (i < n) ? deg[i] : 0;
    s[threadIdx.x] = v;
    __syncthreads();
    for (int off = 1; off < SCAN_B; off <<= 1) {
        int t = (threadIdx.x >= off) ? s[threadIdx.x - off] : 0;
        __syncthreads();
        s[threadIdx.x] += t;
        __syncthreads();
    }
    if (i < n) incl[i] = s[threadIdx.x];
    if (threadIdx.x == SCAN_B - 1) bsum[blockIdx.x] = s[SCAN_B - 1];
}

__global__ void scan_bsum(const int* __restrict__ bsum, int* __restrict__ bex, int nb)
{
    if (threadIdx.x == 0 && blockIdx.x == 0) {
        int run = 0;
        for (int b = 0; b < nb; ++b) { bex[b] = run; run += bsum[b]; }
    }
}

__global__ void finalize_off(const int* __restrict__ deg, const int* __restrict__ incl,
                             const int* __restrict__ bex, int* __restrict__ off,
                             int* __restrict__ cursor, int n)
{
    int i = blockIdx.x * blockDim.x + threadIdx.x;
    if (i < n) { off[i] = incl[i] - deg[i] + bex[i / SCAN_B]; cursor[i] = 0; }
}

__global__ void edge_scatter(const int* __restrict__ ei, const int* __restrict__ off,
                             int* __restrict__ cursor, int* __restrict__ csr_src)
{
    for (int e = blockIdx.x * blockDim.x + threadIdx.x; e < E_TOT; e += gridDim.x * blockDim.x) {
        int s = (e < E_EDGES) ? ei[e] : (e - E_EDGES);
        int d = (e < E_EDGES) ? ei[E_EDGES + e] : (e - E_EDGES);
        int slot = off[d] + atomicAdd(&cursor[d], 1);
        csr_src[slot] = s;
    }
}

// ---------------- layer-1 aggregation: wave per node (frozen at r5 state) ----------------
__global__ __launch_bounds__(256) void agg1_kernel(const float* __restrict__ h1,
                                                   const int* __restrict__ csr_src,
                                                   const int* __restrict__ off,
                                                   const int* __restrict__ deg,
                                                   const float* __restrict__ a_src,
                                                   const float* __restrict__ a_dst,
                                                   const float* __restrict__ b1,
                                                   float* __restrict__ hE)
{
    const int wave = threadIdx.x >> 6, lane = threadIdx.x & 63;
    const int n = blockIdx.x * 4 + wave;
    if (n >= N_NODES) return;
    const int h = lane >> 4;
    const float adn = a_dst[n * 4 + h];
    const int st = off[n], cnt = deg[n];
    float4 acc = make_float4(0.f, 0.f, 0.f, 0.f);
    float dsum = 0.f;

    int s_cur = csr_src[st];                           // deg >= 1 (self-loop)
    int s_nxt = (cnt > 1) ? csr_src[st + 1] : s_cur;
    float a_cur = a_src[s_cur * 4 + h];
    float4 v_cur = *(const float4*)(h1 + (size_t)s_cur * D1 + lane * 4);

    for (int j = 0; j < cnt; ++j) {
        float a_nxt = a_src[s_nxt * 4 + h];
        float4 v_nxt = *(const float4*)(h1 + (size_t)s_nxt * D1 + lane * 4);
        int s_n2 = (j + 2 < cnt) ? csr_src[st + j + 2] : s_nxt;

        float al = a_cur + adn;
        al = (al > 0.f) ? al : NEG_SLOPE * al;
        float ex = __expf(al);
        dsum += ex;
        acc.x += ex * v_cur.x; acc.y += ex * v_cur.y;
        acc.z += ex * v_cur.z; acc.w += ex * v_cur.w;

        a_cur = a_nxt; v_cur = v_nxt; s_nxt = s_n2;
    }
    const float inv = 1.f / (dsum + 1e-16f);
    float4 bb = *(const float4*)(b1 + lane * 4);
    nfloat4 o;
    o.x = acc.x * inv + bb.x;
    o.y = acc.y * inv + bb.y;
    o.z = acc.z * inv + bb.z;
    o.w = acc.w * inv + bb.w;
    o.x = (o.x > 0.f) ? o.x : expm1f(o.x);
    o.y = (o.y > 0.f) ? o.y : expm1f(o.y);
    o.z = (o.z > 0.f) ? o.z : expm1f(o.z);
    o.w = (o.w > 0.f) ? o.w : expm1f(o.w);
    __builtin_nontemporal_store(o, (nfloat4*)(hE + (size_t)n * D1 + lane * 4));
}

// ---------------- layer-2 aggregation + register-accumulated mean-pool ----------------
__global__ __launch_bounds__(256) void agg2_pool_kernel(const float* __restrict__ h2,
                                                        const int* __restrict__ csr_src,
                                                        const int* __restrict__ off,
                                                        const int* __restrict__ deg,
                                                        const float* __restrict__ a_src,
                                                        const float* __restrict__ a_dst,
                                                        const float* __restrict__ b2,
                                                        const int* __restrict__ batch,
                                                        float* __restrict__ pool,
                                                        float* __restrict__ cntg)
{
    const int wave = threadIdx.x >> 6, lane = threadIdx.x & 63;
    const int wgid = blockIdx.x * 4 + wave;
    const int n0 = wgid * CHUNK2;
    if (n0 >= N_NODES) return;
    const int n1 = (n0 + CHUNK2 < N_NODES) ? n0 + CHUNK2 : N_NODES;
    const float bb = b2[lane];

    float poolacc = 0.f, ccur = 0.f;
    int gcur = batch[n0];

    for (int n = n0; n < n1; ++n) {
        const float adn = a_dst[n];
        const int st = off[n], cnt = deg[n];
        float acc = 0.f, dsum = 0.f;

        int s_cur = csr_src[st];
        int s_nxt = (cnt > 1) ? csr_src[st + 1] : s_cur;
        float a_cur = a_src[s_cur];
        float v_cur = h2[(size_t)s_cur * HID + lane];

        for (int j = 0; j < cnt; ++j) {
            float a_nxt = a_src[s_nxt];
            float v_nxt = h2[(size_t)s_nxt * HID + lane];
            int s_n2 = (j + 2 < cnt) ? csr_src[st + j + 2] : s_nxt;

            float al = a_cur + adn;
            al = (al > 0.f) ? al : NEG_SLOPE * al;
            float ex = __expf(al);
            dsum += ex;
            acc += ex * v_cur;

            a_cur = a_nxt; v_cur = v_nxt; s_nxt = s_n2;
        }
        float val = acc / (dsum + 1e-16f) + bb;
        int g = batch[n];
        if (g != gcur) {
#if defined(__AMDGCN__)
            unsafeAtomicAdd(&pool[gcur * HID + lane], poolacc);
            if (lane == 0) unsafeAtomicAdd(&cntg[gcur], ccur);
#else
            atomicAdd(&pool[gcur * HID + lane], poolacc);
            if (lane == 0) atomicAdd(&cntg[gcur], ccur);
#endif
            poolacc = 0.f; ccur = 0.f; gcur = g;
        }
        poolacc += val;
        ccur += 1.f;
    }
#if defined(__AMDGCN__)
    unsafeAtomicAdd(&pool[gcur * HID + lane], poolacc);
    if (lane == 0) unsafeAtomicAdd(&cntg[gcur], ccur);
#else
    atomicAdd(&pool[gcur * HID + lane], poolacc);
    if (lane == 0) atomicAdd(&cntg[gcur], ccur);
#endif
}

// ---------------- head: mean, relu MLP, logits ----------------
__global__ void head_kernel(const float* __restrict__ pool, const float* __restrict__ cntg,
                            const float* __restrict__ W3, const float* __restrict__ b3,
                            const float* __restrict__ W4, const float* __restrict__ b4,
                            float* __restrict__ out)
{
    int g = threadIdx.x;
    if (g >= G_GRAPHS) return;
    float invc = 1.f / fmaxf(cntg[g], 1.f);
    float emb[HID];
#pragma unroll
    for (int k = 0; k < HID; ++k) emb[k] = pool[g * HID + k] * invc;
    float z[32];
    for (int j = 0; j < 32; ++j) {
        float s = b3[j];
        for (int k = 0; k < HID; ++k) s += emb[k] * W3[k * 32 + j];
        z[j] = fmaxf(s, 0.f);
    }
    for (int d = 0; d < 2; ++d) {
        float s = b4[d];
        for (int j = 0; j < 32; ++j) s += z[j] * W4[j * 2 + d];
        out[g * 2 + d] = s;
    }
}

extern "C" void kernel_launch(void* const* d_in, const int* in_sizes, int n_in,
                              void* d_out, int out_size, void* d_ws, size_t ws_size,
                              hipStream_t stream)
{
    const float* x     = (const float*)d_in[0];
    const int*   ei    = (const int*)d_in[1];
    const int*   batch = (const int*)d_in[2];
    const float* W1    = (const float*)d_in[3];
    const float* as1w  = (const float*)d_in[4];
    const float* ad1w  = (const float*)d_in[5];
    const float* b1    = (const float*)d_in[6];
    const float* W2    = (const float*)d_in[7];
    const float* as2w  = (const float*)d_in[8];
    const float* ad2w  = (const float*)d_in[9];
    const float* b2    = (const float*)d_in[10];
    const float* W3    = (const float*)d_in[11];
    const float* b3    = (const float*)d_in[12];
    const float* W4    = (const float*)d_in[13];
    const float* b4    = (const float*)d_in[14];
    float* out = (float*)d_out;

    char* ws = (char*)d_ws;
    size_t o = 0;
    auto alloc = [&](size_t bytes) -> void* {
        void* p = ws + o;
        o += (bytes + 255) & ~(size_t)255;
        return p;
    };
    float* h1   = (float*)alloc((size_t)N_NODES * D1 * 4);
    float* hE   = (float*)alloc((size_t)N_NODES * D1 * 4);
    float* h2   = h1;                                        // alias: h1 dead after agg1
    float* a_s1 = (float*)alloc((size_t)N_NODES * 4 * 4);
    float* a_d1 = (float*)alloc((size_t)N_NODES * 4 * 4);
    float* a_s2 = (float*)alloc((size_t)N_NODES * 4);
    float* a_d2 = (float*)alloc((size_t)N_NODES * 4);
    int*   deg    = (int*)alloc((size_t)N_NODES * 4);
    int*   incl   = (int*)alloc((size_t)N_NODES * 4);
    int*   offv   = (int*)alloc((size_t)N_NODES * 4);
    int*   cursor = (int*)alloc((size_t)N_NODES * 4);
    int*   bsum   = (int*)alloc(128 * 4);
    int*   bex    = (int*)alloc(128 * 4);
    int*   csr    = (int*)alloc((size_t)E_TOT * 4);
    float* pool   = (float*)alloc((size_t)G_GRAPHS * HID * 4);
    float* cntg   = (float*)alloc((size_t)G_GRAPHS * 4);

    (void)hipMemsetAsync(deg, 0, (size_t)N_NODES * 4, stream);
    (void)hipMemsetAsync(pool, 0, (size_t)G_GRAPHS * HID * 4, stream);
    (void)hipMemsetAsync(cntg, 0, (size_t)G_GRAPHS * 4, stream);

    const int nblk_nodes = (N_NODES + 3) / 4;
    const int nscan = (N_NODES + SCAN_B - 1) / SCAN_B;

    // GEMM1 + att1: h1 = x @ W1, a_s1/a_d1 in epilogue
    gemm1_att1<<<dim3(HEADS, (N_NODES + 127) / 128), 256, 0, stream>>>(x, W1, h1, as1w, ad1w, a_s1, a_d1);

    // CSR build (shared by both layers)
    edge_hist<<<4096, 256, 0, stream>>>(ei, deg);
    scan_block<<<nscan, SCAN_B, 0, stream>>>(deg, incl, bsum, N_NODES);
    scan_bsum<<<1, 64, 0, stream>>>(bsum, bex, nscan);
    finalize_off<<<(N_NODES + 255) / 256, 256, 0, stream>>>(deg, incl, bex, offv, cursor, N_NODES);
    edge_scatter<<<4096, 256, 0, stream>>>(ei, offv, cursor, csr);

    // layer-1 gather-aggregate, fused softmax + b1 + ELU
    agg1_kernel<<<nblk_nodes, 256, 0, stream>>>(h1, csr, offv, deg, a_s1, a_d1, b1, hE);

    // GEMM2 + att2: h2 = hE @ W2, a_s2/a_d2 in epilogue
    gemm2_att2<<<dim3(1, (N_NODES + 63) / 64), 256, 0, stream>>>(hE, W2, h2, as2w, ad2w, a_s2, a_d2);

    // layer-2 gather-aggregate + register-accumulated mean-pool
    const int nwaves2 = (N_NODES + CHUNK2 - 1) / CHUNK2;
    agg2_pool_kernel<<<(nwaves2 + 3) / 4, 256, 0, stream>>>(h2, csr, offv, deg, a_s2, a_d2, b2, batch, pool, cntg);

    // head MLP
    head_kernel<<<1, 64, 0, stream>>>(pool, cntg, W3, b3, W4, b4, out);
}

// Round 7
// 1019.037 us; speedup vs baseline: 1.1020x; 1.0035x over previous
//
#include <hip/hip_runtime.h>
#include <math.h>

#define N_NODES 100000
#define E_EDGES 1600000
#define E_TOT   (E_EDGES + N_NODES)
#define G_GRAPHS 64
#define IN_DIM 256
#define HID 64
#define HEADS 4
#define D1 256            // HEADS*HID
#define NEG_SLOPE 0.2f
#define SCAN_B 1024
#define CHUNK2 16         // nodes per wave in agg2

typedef float nfloat4 __attribute__((ext_vector_type(4)));

// ---------------- fused GEMM + attention dots ----------------
// C[M,Nc] = A[M,256] @ B[256,Nc]; tile 128x64, 256 thr, 8x4 microtile.
// blockIdx.x = 64-col tile (= head for layer 1, 0 for layer 2); attention
// dots for this col-tile computed in-epilogue via 16-lane shuffle.
// Register-prefetch double buffer: next k-tile's global loads are issued
// right after the first barrier and consumed after the compute block, so
// global latency overlaps the ~1024-cy FMA burst.
__global__ __launch_bounds__(256) void gemm_att(const float* __restrict__ A,
                                                const float* __restrict__ B,
                                                float* __restrict__ C,
                                                int Nc,
                                                const float* __restrict__ att_src,
                                                const float* __restrict__ att_dst,
                                                float* __restrict__ a_srcO,
                                                float* __restrict__ a_dstO,
                                                int astride)
{
    __shared__ float AsT[16][132];   // [k][m] 128 rows (+4 pad)
    __shared__ float Bs[16][68];     // [k][n] 64 cols (+4 pad)
    const int tid = threadIdx.x, tx = tid & 15, ty = tid >> 4;
    const int bx = blockIdx.x, bm = blockIdx.y * 128, bn = bx * 64;
    const int row0 = tid >> 2, kq = (tid & 3) * 4;
    float acc[8][4] = {};

    float4 a0, a1, bv;
    {
        int m = bm + row0;
        a0 = (m < N_NODES) ? *(const float4*)(A + (size_t)m * 256 + kq) : make_float4(0.f, 0.f, 0.f, 0.f);
        m = bm + row0 + 64;
        a1 = (m < N_NODES) ? *(const float4*)(A + (size_t)m * 256 + kq) : make_float4(0.f, 0.f, 0.f, 0.f);
        bv = *(const float4*)(B + (size_t)ty * Nc + bn + tx * 4);
    }

    for (int k0 = 0; k0 < 256; k0 += 16) {
        AsT[kq + 0][row0] = a0.x; AsT[kq + 1][row0] = a0.y;
        AsT[kq + 2][row0] = a0.z; AsT[kq + 3][row0] = a0.w;
        AsT[kq + 0][row0 + 64] = a1.x; AsT[kq + 1][row0 + 64] = a1.y;
        AsT[kq + 2][row0 + 64] = a1.z; AsT[kq + 3][row0 + 64] = a1.w;
        *(float4*)(&Bs[ty][tx * 4]) = bv;
        __syncthreads();

        if (k0 + 16 < 256) {                       // prefetch next k-tile
            const int kn = k0 + 16;
            int m = bm + row0;
            a0 = (m < N_NODES) ? *(const float4*)(A + (size_t)m * 256 + kn + kq) : make_float4(0.f, 0.f, 0.f, 0.f);
            m = bm + row0 + 64;
            a1 = (m < N_NODES) ? *(const float4*)(A + (size_t)m * 256 + kn + kq) : make_float4(0.f, 0.f, 0.f, 0.f);
            bv = *(const float4*)(B + (size_t)(kn + ty) * Nc + bn + tx * 4);
        }
#pragma unroll
        for (int k = 0; k < 16; ++k) {
            float a[8], b[4];
            *(float4*)(&a[0]) = *(const float4*)(&AsT[k][ty * 4]);
            *(float4*)(&a[4]) = *(const float4*)(&AsT[k][64 + ty * 4]);
            *(float4*)(&b[0]) = *(const float4*)(&Bs[k][tx * 4]);
#pragma unroll
            for (int i = 0; i < 8; ++i)
#pragma unroll
                for (int j = 0; j < 4; ++j)
                    acc[i][j] += a[i] * b[j];
        }
        __syncthreads();
    }

    const float4 sv = *(const float4*)(att_src + bn + tx * 4);
    const float4 dv = *(const float4*)(att_dst + bn + tx * 4);
#pragma unroll
    for (int i = 0; i < 8; ++i) {
        int m = bm + ((i < 4) ? (ty * 4 + i) : (64 + ty * 4 + (i - 4)));
        float ps = acc[i][0] * sv.x + acc[i][1] * sv.y + acc[i][2] * sv.z + acc[i][3] * sv.w;
        float pd = acc[i][0] * dv.x + acc[i][1] * dv.y + acc[i][2] * dv.z + acc[i][3] * dv.w;
#pragma unroll
        for (int o = 1; o < 16; o <<= 1) { ps += __shfl_xor(ps, o); pd += __shfl_xor(pd, o); }
        if (m < N_NODES) {
            *(float4*)(C + (size_t)m * Nc + bn + tx * 4) =
                make_float4(acc[i][0], acc[i][1], acc[i][2], acc[i][3]);
            if (tx == 0) { a_srcO[m * astride + bx] = ps; a_dstO[m * astride + bx] = pd; }
        }
    }
}

// ---------------- CSR build: histogram, scan, scatter ----------------
__global__ void edge_hist(const int* __restrict__ ei, int* __restrict__ deg)
{
    for (int e = blockIdx.x * blockDim.x + threadIdx.x; e < E_TOT; e += gridDim.x * blockDim.x) {
        int d = (e < E_EDGES) ? ei[E_EDGES + e] : (e - E_EDGES);
        atomicAdd(&deg[d], 1);
    }
}

__global__ __launch_bounds__(SCAN_B) void scan_block(const int* __restrict__ deg,
                                                     int* __restrict__ incl,
                                                     int* __restrict__ bsum, int n)
{
    __shared__ int s[SCAN_B];
    int i = blockIdx.x * SCAN_B + threadIdx.x;
    int v = (i < n) ? deg[i] : 0;
    s[threadIdx.x] = v;
    __syncthreads();
    for (int off = 1; off < SCAN_B; off <<= 1) {
        int t = (threadIdx.x >= off) ? s[threadIdx.x - off] : 0;
        __syncthreads();
        s[threadIdx.x] += t;
        __syncthreads();
    }
    if (i < n) incl[i] = s[threadIdx.x];
    if (threadIdx.x == SCAN_B - 1) bsum[blockIdx.x] = s[SCAN_B - 1];
}

// parallel LDS scan over the <=128 block sums (was a single-thread serial loop)
__global__ void scan_bsum(const int* __restrict__ bsum, int* __restrict__ bex, int nb)
{
    __shared__ int s[128];
    int i = threadIdx.x;
    int v = (i < nb) ? bsum[i] : 0;
    s[i] = v;
    __syncthreads();
    for (int off = 1; off < 128; off <<= 1) {
        int t = (i >= off) ? s[i - off] : 0;
        __syncthreads();
        s[i] += t;
        __syncthreads();
    }
    if (i < nb) bex[i] = s[i] - v;   // exclusive
}

__global__ void finalize_off(const int* __restrict__ deg, const int* __restrict__ incl,
                             const int* __restrict__ bex, int* __restrict__ off,
                             int* __restrict__ cursor, int n)
{
    int i = blockIdx.x * blockDim.x + threadIdx.x;
    if (i < n) { off[i] = incl[i] - deg[i] + bex[i / SCAN_B]; cursor[i] = 0; }
}

__global__ void edge_scatter(const int* __restrict__ ei, const int* __restrict__ off,
                             int* __restrict__ cursor, int* __restrict__ csr_src)
{
    for (int e = blockIdx.x * blockDim.x + threadIdx.x; e < E_TOT; e += gridDim.x * blockDim.x) {
        int s = (e < E_EDGES) ? ei[e] : (e - E_EDGES);
        int d = (e < E_EDGES) ? ei[E_EDGES + e] : (e - E_EDGES);
        int slot = off[d] + atomicAdd(&cursor[d], 1);
        csr_src[slot] = s;
    }
}

// ---------------- layer-1 aggregation: wave per node (frozen) ----------------
__global__ __launch_bounds__(256) void agg1_kernel(const float* __restrict__ h1,
                                                   const int* __restrict__ csr_src,
                                                   const int* __restrict__ off,
                                                   const int* __restrict__ deg,
                                                   const float* __restrict__ a_src,
                                                   const float* __restrict__ a_dst,
                                                   const float* __restrict__ b1,
                                                   float* __restrict__ hE)
{
    const int wave = threadIdx.x >> 6, lane = threadIdx.x & 63;
    const int n = blockIdx.x * 4 + wave;
    if (n >= N_NODES) return;
    const int h = lane >> 4;
    const float adn = a_dst[n * 4 + h];
    const int st = off[n], cnt = deg[n];
    float4 acc = make_float4(0.f, 0.f, 0.f, 0.f);
    float dsum = 0.f;

    int s_cur = csr_src[st];                           // deg >= 1 (self-loop)
    int s_nxt = (cnt > 1) ? csr_src[st + 1] : s_cur;
    float a_cur = a_src[s_cur * 4 + h];
    float4 v_cur = *(const float4*)(h1 + (size_t)s_cur * D1 + lane * 4);

    for (int j = 0; j < cnt; ++j) {
        float a_nxt = a_src[s_nxt * 4 + h];
        float4 v_nxt = *(const float4*)(h1 + (size_t)s_nxt * D1 + lane * 4);
        int s_n2 = (j + 2 < cnt) ? csr_src[st + j + 2] : s_nxt;

        float al = a_cur + adn;
        al = (al > 0.f) ? al : NEG_SLOPE * al;
        float ex = __expf(al);
        dsum += ex;
        acc.x += ex * v_cur.x; acc.y += ex * v_cur.y;
        acc.z += ex * v_cur.z; acc.w += ex * v_cur.w;

        a_cur = a_nxt; v_cur = v_nxt; s_nxt = s_n2;
    }
    const float inv = 1.f / (dsum + 1e-16f);
    float4 bb = *(const float4*)(b1 + lane * 4);
    nfloat4 o;
    o.x = acc.x * inv + bb.x;
    o.y = acc.y * inv + bb.y;
    o.z = acc.z * inv + bb.z;
    o.w = acc.w * inv + bb.w;
    o.x = (o.x > 0.f) ? o.x : expm1f(o.x);
    o.y = (o.y > 0.f) ? o.y : expm1f(o.y);
    o.z = (o.z > 0.f) ? o.z : expm1f(o.z);
    o.w = (o.w > 0.f) ? o.w : expm1f(o.w);
    __builtin_nontemporal_store(o, (nfloat4*)(hE + (size_t)n * D1 + lane * 4));
}

// ---------------- layer-2 aggregation + register-accumulated mean-pool ----------------
// 2-wide edge processing (two independent load streams) + 1-deep pipeline.
__global__ __launch_bounds__(256) void agg2_pool_kernel(const float* __restrict__ h2,
                                                        const int* __restrict__ csr_src,
                                                        const int* __restrict__ off,
                                                        const int* __restrict__ deg,
                                                        const float* __restrict__ a_src,
                                                        const float* __restrict__ a_dst,
                                                        const float* __restrict__ b2,
                                                        const int* __restrict__ batch,
                                                        float* __restrict__ pool,
                                                        float* __restrict__ cntg)
{
    const int wave = threadIdx.x >> 6, lane = threadIdx.x & 63;
    const int wgid = blockIdx.x * 4 + wave;
    const int n0 = wgid * CHUNK2;
    if (n0 >= N_NODES) return;
    const int n1 = (n0 + CHUNK2 < N_NODES) ? n0 + CHUNK2 : N_NODES;
    const float bb = b2[lane];

    float poolacc = 0.f, ccur = 0.f;
    int gcur = batch[n0];

    for (int n = n0; n < n1; ++n) {
        const float adn = a_dst[n];
        const int st = off[n], cnt = deg[n];
        float acc = 0.f, dsum = 0.f;
        const int npairs = cnt >> 1;

        if (npairs > 0) {
            int s0 = csr_src[st], s1 = csr_src[st + 1];
            float A0 = a_src[s0], A1 = a_src[s1];
            float V0 = h2[(size_t)s0 * HID + lane], V1 = h2[(size_t)s1 * HID + lane];
            for (int p = 0; p < npairs; ++p) {
                int q = (p + 1 < npairs) ? st + 2 * (p + 1) : st;   // dummy=pair0 (cache-hot)
                int ns0 = csr_src[q], ns1 = csr_src[q + 1];
                float nA0 = a_src[ns0], nA1 = a_src[ns1];
                float nV0 = h2[(size_t)ns0 * HID + lane], nV1 = h2[(size_t)ns1 * HID + lane];

                float al0 = A0 + adn; al0 = (al0 > 0.f) ? al0 : NEG_SLOPE * al0;
                float al1 = A1 + adn; al1 = (al1 > 0.f) ? al1 : NEG_SLOPE * al1;
                float e0 = __expf(al0), e1 = __expf(al1);
                dsum += e0 + e1;
                acc += e0 * V0 + e1 * V1;

                A0 = nA0; V0 = nV0; A1 = nA1; V1 = nV1;
            }
        }
        if (cnt & 1) {                    // tail edge
            int s = csr_src[st + cnt - 1];
            float a = a_src[s];
            float v = h2[(size_t)s * HID + lane];
            float al = a + adn; al = (al > 0.f) ? al : NEG_SLOPE * al;
            float e = __expf(al);
            dsum += e; acc += e * v;
        }

        float val = acc / (dsum + 1e-16f) + bb;
        int g = batch[n];
        if (g != gcur) {
#if defined(__AMDGCN__)
            unsafeAtomicAdd(&pool[gcur * HID + lane], poolacc);
            if (lane == 0) unsafeAtomicAdd(&cntg[gcur], ccur);
#else
            atomicAdd(&pool[gcur * HID + lane], poolacc);
            if (lane == 0) atomicAdd(&cntg[gcur], ccur);
#endif
            poolacc = 0.f; ccur = 0.f; gcur = g;
        }
        poolacc += val;
        ccur += 1.f;
    }
#if defined(__AMDGCN__)
    unsafeAtomicAdd(&pool[gcur * HID + lane], poolacc);
    if (lane == 0) unsafeAtomicAdd(&cntg[gcur], ccur);
#else
    atomicAdd(&pool[gcur * HID + lane], poolacc);
    if (lane == 0) atomicAdd(&cntg[gcur], ccur);
#endif
}

// ---------------- head: mean, relu MLP, logits ----------------
__global__ void head_kernel(const float* __restrict__ pool, const float* __restrict__ cntg,
                            const float* __restrict__ W3, const float* __restrict__ b3,
                            const float* __restrict__ W4, const float* __restrict__ b4,
                            float* __restrict__ out)
{
    int g = threadIdx.x;
    if (g >= G_GRAPHS) return;
    float invc = 1.f / fmaxf(cntg[g], 1.f);
    float emb[HID];
#pragma unroll
    for (int k = 0; k < HID; ++k) emb[k] = pool[g * HID + k] * invc;
    float z[32];
    for (int j = 0; j < 32; ++j) {
        float s = b3[j];
        for (int k = 0; k < HID; ++k) s += emb[k] * W3[k * 32 + j];
        z[j] = fmaxf(s, 0.f);
    }
    for (int d = 0; d < 2; ++d) {
        float s = b4[d];
        for (int j = 0; j < 32; ++j) s += z[j] * W4[j * 2 + d];
        out[g * 2 + d] = s;
    }
}

extern "C" void kernel_launch(void* const* d_in, const int* in_sizes, int n_in,
                              void* d_out, int out_size, void* d_ws, size_t ws_size,
                              hipStream_t stream)
{
    const float* x     = (const float*)d_in[0];
    const int*   ei    = (const int*)d_in[1];
    const int*   batch = (const int*)d_in[2];
    const float* W1    = (const float*)d_in[3];
    const float* as1w  = (const float*)d_in[4];
    const float* ad1w  = (const float*)d_in[5];
    const float* b1    = (const float*)d_in[6];
    const float* W2    = (const float*)d_in[7];
    const float* as2w  = (const float*)d_in[8];
    const float* ad2w  = (const float*)d_in[9];
    const float* b2    = (const float*)d_in[10];
    const float* W3    = (const float*)d_in[11];
    const float* b3    = (const float*)d_in[12];
    const float* W4    = (const float*)d_in[13];
    const float* b4    = (const float*)d_in[14];
    float* out = (float*)d_out;

    char* ws = (char*)d_ws;
    size_t o = 0;
    auto alloc = [&](size_t bytes) -> void* {
        void* p = ws + o;
        o += (bytes + 255) & ~(size_t)255;
        return p;
    };
    float* h1   = (float*)alloc((size_t)N_NODES * D1 * 4);
    float* hE   = (float*)alloc((size_t)N_NODES * D1 * 4);
    float* h2   = h1;                                        // alias: h1 dead after agg1
    float* a_s1 = (float*)alloc((size_t)N_NODES * 4 * 4);
    float* a_d1 = (float*)alloc((size_t)N_NODES * 4 * 4);
    float* a_s2 = (float*)alloc((size_t)N_NODES * 4);
    float* a_d2 = (float*)alloc((size_t)N_NODES * 4);
    int*   deg    = (int*)alloc((size_t)N_NODES * 4);
    int*   incl   = (int*)alloc((size_t)N_NODES * 4);
    int*   offv   = (int*)alloc((size_t)N_NODES * 4);
    int*   cursor = (int*)alloc((size_t)N_NODES * 4);
    int*   bsum   = (int*)alloc(128 * 4);
    int*   bex    = (int*)alloc(128 * 4);
    int*   csr    = (int*)alloc((size_t)E_TOT * 4);
    float* pool   = (float*)alloc((size_t)G_GRAPHS * HID * 4);
    float* cntg   = (float*)alloc((size_t)G_GRAPHS * 4);

    (void)hipMemsetAsync(deg, 0, (size_t)N_NODES * 4, stream);
    (void)hipMemsetAsync(pool, 0, (size_t)G_GRAPHS * HID * 4, stream);
    (void)hipMemsetAsync(cntg, 0, (size_t)G_GRAPHS * 4, stream);

    const int nblk_nodes = (N_NODES + 3) / 4;
    const int nscan = (N_NODES + SCAN_B - 1) / SCAN_B;

    // GEMM1 + att1: h1 = x @ W1 (Nc=256, 4 head col-tiles, astride=4)
    gemm_att<<<dim3(HEADS, (N_NODES + 127) / 128), 256, 0, stream>>>(
        x, W1, h1, D1, as1w, ad1w, a_s1, a_d1, 4);

    // CSR build (shared by both layers)
    edge_hist<<<4096, 256, 0, stream>>>(ei, deg);
    scan_block<<<nscan, SCAN_B, 0, stream>>>(deg, incl, bsum, N_NODES);
    scan_bsum<<<1, 128, 0, stream>>>(bsum, bex, nscan);
    finalize_off<<<(N_NODES + 255) / 256, 256, 0, stream>>>(deg, incl, bex, offv, cursor, N_NODES);
    edge_scatter<<<4096, 256, 0, stream>>>(ei, offv, cursor, csr);

    // layer-1 gather-aggregate, fused softmax + b1 + ELU
    agg1_kernel<<<nblk_nodes, 256, 0, stream>>>(h1, csr, offv, deg, a_s1, a_d1, b1, hE);

    // GEMM2 + att2: h2 = hE @ W2 (Nc=64, single col-tile, astride=1)
    gemm_att<<<dim3(1, (N_NODES + 127) / 128), 256, 0, stream>>>(
        hE, W2, h2, HID, as2w, ad2w, a_s2, a_d2, 1);

    // layer-2 gather-aggregate + register-accumulated mean-pool
    const int nwaves2 = (N_NODES + CHUNK2 - 1) / CHUNK2;
    agg2_pool_kernel<<<(nwaves2 + 3) / 4, 256, 0, stream>>>(h2, csr, offv, deg, a_s2, a_d2, b2, batch, pool, cntg);

    // head MLP
    head_kernel<<<1, 64, 0, stream>>>(pool, cntg, W3, b3, W4, b4, out);
}

// Round 8
// 887.999 us; speedup vs baseline: 1.2646x; 1.1476x over previous
//
#include <hip/hip_runtime.h>
#include <math.h>

#define N_NODES 100000
#define E_EDGES 1600000
#define E_TOT   (E_EDGES + N_NODES)
#define G_GRAPHS 64
#define IN_DIM 256
#define HID 64
#define HEADS 4
#define D1 256            // HEADS*HID
#define NEG_SLOPE 0.2f
#define SCAN_B 1024
#define CHUNK2 16         // nodes per wave in agg2

typedef float nfloat4 __attribute__((ext_vector_type(4)));

// bf16 <-> fp32 (RNE encode, exact shift decode)
__device__ __forceinline__ float bf2f(unsigned short u) {
    unsigned int t = ((unsigned int)u) << 16;
    return __builtin_bit_cast(float, t);
}
__device__ __forceinline__ unsigned short f2bf(float f) {
    unsigned int u = __builtin_bit_cast(unsigned int, f);
    u += 0x7FFF + ((u >> 16) & 1);
    return (unsigned short)(u >> 16);
}

// ---------------- fused GEMM + attention dots, bf16 output ----------------
// C[M,Nc](bf16) = A[M,256](fp32) @ B[256,Nc](fp32); tile 128x64, 8x4 microtile.
// Attention dots computed from fp32 accumulators in-epilogue (full precision).
__global__ __launch_bounds__(256) void gemm_att(const float* __restrict__ A,
                                                const float* __restrict__ B,
                                                unsigned short* __restrict__ C,
                                                int Nc,
                                                const float* __restrict__ att_src,
                                                const float* __restrict__ att_dst,
                                                float* __restrict__ a_srcO,
                                                float* __restrict__ a_dstO,
                                                int astride)
{
    __shared__ float AsT[16][132];   // [k][m] 128 rows (+4 pad)
    __shared__ float Bs[16][68];     // [k][n] 64 cols (+4 pad)
    const int tid = threadIdx.x, tx = tid & 15, ty = tid >> 4;
    const int bx = blockIdx.x, bm = blockIdx.y * 128, bn = bx * 64;
    const int row0 = tid >> 2, kq = (tid & 3) * 4;
    float acc[8][4] = {};

    float4 a0, a1, bv;
    {
        int m = bm + row0;
        a0 = (m < N_NODES) ? *(const float4*)(A + (size_t)m * 256 + kq) : make_float4(0.f, 0.f, 0.f, 0.f);
        m = bm + row0 + 64;
        a1 = (m < N_NODES) ? *(const float4*)(A + (size_t)m * 256 + kq) : make_float4(0.f, 0.f, 0.f, 0.f);
        bv = *(const float4*)(B + (size_t)ty * Nc + bn + tx * 4);
    }

    for (int k0 = 0; k0 < 256; k0 += 16) {
        AsT[kq + 0][row0] = a0.x; AsT[kq + 1][row0] = a0.y;
        AsT[kq + 2][row0] = a0.z; AsT[kq + 3][row0] = a0.w;
        AsT[kq + 0][row0 + 64] = a1.x; AsT[kq + 1][row0 + 64] = a1.y;
        AsT[kq + 2][row0 + 64] = a1.z; AsT[kq + 3][row0 + 64] = a1.w;
        *(float4*)(&Bs[ty][tx * 4]) = bv;
        __syncthreads();

        if (k0 + 16 < 256) {                       // prefetch next k-tile
            const int kn = k0 + 16;
            int m = bm + row0;
            a0 = (m < N_NODES) ? *(const float4*)(A + (size_t)m * 256 + kn + kq) : make_float4(0.f, 0.f, 0.f, 0.f);
            m = bm + row0 + 64;
            a1 = (m < N_NODES) ? *(const float4*)(A + (size_t)m * 256 + kn + kq) : make_float4(0.f, 0.f, 0.f, 0.f);
            bv = *(const float4*)(B + (size_t)(kn + ty) * Nc + bn + tx * 4);
        }
#pragma unroll
        for (int k = 0; k < 16; ++k) {
            float a[8], b[4];
            *(float4*)(&a[0]) = *(const float4*)(&AsT[k][ty * 4]);
            *(float4*)(&a[4]) = *(const float4*)(&AsT[k][64 + ty * 4]);
            *(float4*)(&b[0]) = *(const float4*)(&Bs[k][tx * 4]);
#pragma unroll
            for (int i = 0; i < 8; ++i)
#pragma unroll
                for (int j = 0; j < 4; ++j)
                    acc[i][j] += a[i] * b[j];
        }
        __syncthreads();
    }

    const float4 sv = *(const float4*)(att_src + bn + tx * 4);
    const float4 dv = *(const float4*)(att_dst + bn + tx * 4);
#pragma unroll
    for (int i = 0; i < 8; ++i) {
        int m = bm + ((i < 4) ? (ty * 4 + i) : (64 + ty * 4 + (i - 4)));
        float ps = acc[i][0] * sv.x + acc[i][1] * sv.y + acc[i][2] * sv.z + acc[i][3] * sv.w;
        float pd = acc[i][0] * dv.x + acc[i][1] * dv.y + acc[i][2] * dv.z + acc[i][3] * dv.w;
#pragma unroll
        for (int o = 1; o < 16; o <<= 1) { ps += __shfl_xor(ps, o); pd += __shfl_xor(pd, o); }
        if (m < N_NODES) {
            ushort4 ov;
            ov.x = f2bf(acc[i][0]); ov.y = f2bf(acc[i][1]);
            ov.z = f2bf(acc[i][2]); ov.w = f2bf(acc[i][3]);
            *(ushort4*)(C + (size_t)m * Nc + bn + tx * 4) = ov;
            if (tx == 0) { a_srcO[m * astride + bx] = ps; a_dstO[m * astride + bx] = pd; }
        }
    }
}

// ---------------- CSR build: histogram, scan, scatter ----------------
__global__ void edge_hist(const int* __restrict__ ei, int* __restrict__ deg)
{
    for (int e = blockIdx.x * blockDim.x + threadIdx.x; e < E_TOT; e += gridDim.x * blockDim.x) {
        int d = (e < E_EDGES) ? ei[E_EDGES + e] : (e - E_EDGES);
        atomicAdd(&deg[d], 1);
    }
}

__global__ __launch_bounds__(SCAN_B) void scan_block(const int* __restrict__ deg,
                                                     int* __restrict__ incl,
                                                     int* __restrict__ bsum, int n)
{
    __shared__ int s[SCAN_B];
    int i = blockIdx.x * SCAN_B + threadIdx.x;
    int v = (i < n) ? deg[i] : 0;
    s[threadIdx.x] = v;
    __syncthreads();
    for (int off = 1; off < SCAN_B; off <<= 1) {
        int t = (threadIdx.x >= off) ? s[threadIdx.x - off] : 0;
        __syncthreads();
        s[threadIdx.x] += t;
        __syncthreads();
    }
    if (i < n) incl[i] = s[threadIdx.x];
    if (threadIdx.x == SCAN_B - 1) bsum[blockIdx.x] = s[SCAN_B - 1];
}

__global__ void scan_bsum(const int* __restrict__ bsum, int* __restrict__ bex, int nb)
{
    __shared__ int s[128];
    int i = threadIdx.x;
    int v = (i < nb) ? bsum[i] : 0;
    s[i] = v;
    __syncthreads();
    for (int off = 1; off < 128; off <<= 1) {
        int t = (i >= off) ? s[i - off] : 0;
        __syncthreads();
        s[i] += t;
        __syncthreads();
    }
    if (i < nb) bex[i] = s[i] - v;   // exclusive
}

__global__ void finalize_off(const int* __restrict__ deg, const int* __restrict__ incl,
                             const int* __restrict__ bex, int* __restrict__ off,
                             int* __restrict__ cursor, int n)
{
    int i = blockIdx.x * blockDim.x + threadIdx.x;
    if (i < n) { off[i] = incl[i] - deg[i] + bex[i / SCAN_B]; cursor[i] = 0; }
}

__global__ void edge_scatter(const int* __restrict__ ei, const int* __restrict__ off,
                             int* __restrict__ cursor, int* __restrict__ csr_src)
{
    for (int e = blockIdx.x * blockDim.x + threadIdx.x; e < E_TOT; e += gridDim.x * blockDim.x) {
        int s = (e < E_EDGES) ? ei[e] : (e - E_EDGES);
        int d = (e < E_EDGES) ? ei[E_EDGES + e] : (e - E_EDGES);
        int slot = off[d] + atomicAdd(&cursor[d], 1);
        csr_src[slot] = s;
    }
}

// ---------------- layer-1 aggregation: wave per node, bf16 payload ----------------
// Gathers h1 rows as bf16 (512 B/row vs 1 KB) -> halves the dominant traffic.
// Attention weights + accumulation stay fp32.
__global__ __launch_bounds__(256) void agg1_kernel(const unsigned short* __restrict__ h1b,
                                                   const int* __restrict__ csr_src,
                                                   const int* __restrict__ off,
                                                   const int* __restrict__ deg,
                                                   const float* __restrict__ a_src,
                                                   const float* __restrict__ a_dst,
                                                   const float* __restrict__ b1,
                                                   float* __restrict__ hE)
{
    const int wave = threadIdx.x >> 6, lane = threadIdx.x & 63;
    const int n = blockIdx.x * 4 + wave;
    if (n >= N_NODES) return;
    const int h = lane >> 4;
    const float adn = a_dst[n * 4 + h];
    const int st = off[n], cnt = deg[n];
    float4 acc = make_float4(0.f, 0.f, 0.f, 0.f);
    float dsum = 0.f;

    int s_cur = csr_src[st];                           // deg >= 1 (self-loop)
    int s_nxt = (cnt > 1) ? csr_src[st + 1] : s_cur;
    float a_cur = a_src[s_cur * 4 + h];
    ushort4 v_cur = *(const ushort4*)(h1b + (size_t)s_cur * D1 + lane * 4);

    for (int j = 0; j < cnt; ++j) {
        float a_nxt = a_src[s_nxt * 4 + h];
        ushort4 v_nxt = *(const ushort4*)(h1b + (size_t)s_nxt * D1 + lane * 4);
        int s_n2 = (j + 2 < cnt) ? csr_src[st + j + 2] : s_nxt;

        float al = a_cur + adn;
        al = (al > 0.f) ? al : NEG_SLOPE * al;
        float ex = __expf(al);
        dsum += ex;
        acc.x += ex * bf2f(v_cur.x); acc.y += ex * bf2f(v_cur.y);
        acc.z += ex * bf2f(v_cur.z); acc.w += ex * bf2f(v_cur.w);

        a_cur = a_nxt; v_cur = v_nxt; s_nxt = s_n2;
    }
    const float inv = 1.f / (dsum + 1e-16f);
    float4 bb = *(const float4*)(b1 + lane * 4);
    nfloat4 o;
    o.x = acc.x * inv + bb.x;
    o.y = acc.y * inv + bb.y;
    o.z = acc.z * inv + bb.z;
    o.w = acc.w * inv + bb.w;
    o.x = (o.x > 0.f) ? o.x : expm1f(o.x);
    o.y = (o.y > 0.f) ? o.y : expm1f(o.y);
    o.z = (o.z > 0.f) ? o.z : expm1f(o.z);
    o.w = (o.w > 0.f) ? o.w : expm1f(o.w);
    __builtin_nontemporal_store(o, (nfloat4*)(hE + (size_t)n * D1 + lane * 4));
}

// ---------------- layer-2 aggregation + register-accumulated mean-pool (bf16 payload) ----------------
__global__ __launch_bounds__(256) void agg2_pool_kernel(const unsigned short* __restrict__ h2b,
                                                        const int* __restrict__ csr_src,
                                                        const int* __restrict__ off,
                                                        const int* __restrict__ deg,
                                                        const float* __restrict__ a_src,
                                                        const float* __restrict__ a_dst,
                                                        const float* __restrict__ b2,
                                                        const int* __restrict__ batch,
                                                        float* __restrict__ pool,
                                                        float* __restrict__ cntg)
{
    const int wave = threadIdx.x >> 6, lane = threadIdx.x & 63;
    const int wgid = blockIdx.x * 4 + wave;
    const int n0 = wgid * CHUNK2;
    if (n0 >= N_NODES) return;
    const int n1 = (n0 + CHUNK2 < N_NODES) ? n0 + CHUNK2 : N_NODES;
    const float bb = b2[lane];

    float poolacc = 0.f, ccur = 0.f;
    int gcur = batch[n0];

    for (int n = n0; n < n1; ++n) {
        const float adn = a_dst[n];
        const int st = off[n], cnt = deg[n];
        float acc = 0.f, dsum = 0.f;
        const int npairs = cnt >> 1;

        if (npairs > 0) {
            int s0 = csr_src[st], s1 = csr_src[st + 1];
            float A0 = a_src[s0], A1 = a_src[s1];
            unsigned short V0 = h2b[(size_t)s0 * HID + lane], V1 = h2b[(size_t)s1 * HID + lane];
            for (int p = 0; p < npairs; ++p) {
                int q = (p + 1 < npairs) ? st + 2 * (p + 1) : st;   // dummy=pair0 (cache-hot)
                int ns0 = csr_src[q], ns1 = csr_src[q + 1];
                float nA0 = a_src[ns0], nA1 = a_src[ns1];
                unsigned short nV0 = h2b[(size_t)ns0 * HID + lane], nV1 = h2b[(size_t)ns1 * HID + lane];

                float al0 = A0 + adn; al0 = (al0 > 0.f) ? al0 : NEG_SLOPE * al0;
                float al1 = A1 + adn; al1 = (al1 > 0.f) ? al1 : NEG_SLOPE * al1;
                float e0 = __expf(al0), e1 = __expf(al1);
                dsum += e0 + e1;
                acc += e0 * bf2f(V0) + e1 * bf2f(V1);

                A0 = nA0; V0 = nV0; A1 = nA1; V1 = nV1;
            }
        }
        if (cnt & 1) {                    // tail edge
            int s = csr_src[st + cnt - 1];
            float a = a_src[s];
            float v = bf2f(h2b[(size_t)s * HID + lane]);
            float al = a + adn; al = (al > 0.f) ? al : NEG_SLOPE * al;
            float e = __expf(al);
            dsum += e; acc += e * v;
        }

        float val = acc / (dsum + 1e-16f) + bb;
        int g = batch[n];
        if (g != gcur) {
#if defined(__AMDGCN__)
            unsafeAtomicAdd(&pool[gcur * HID + lane], poolacc);
            if (lane == 0) unsafeAtomicAdd(&cntg[gcur], ccur);
#else
            atomicAdd(&pool[gcur * HID + lane], poolacc);
            if (lane == 0) atomicAdd(&cntg[gcur], ccur);
#endif
            poolacc = 0.f; ccur = 0.f; gcur = g;
        }
        poolacc += val;
        ccur += 1.f;
    }
#if defined(__AMDGCN__)
    unsafeAtomicAdd(&pool[gcur * HID + lane], poolacc);
    if (lane == 0) unsafeAtomicAdd(&cntg[gcur], ccur);
#else
    atomicAdd(&pool[gcur * HID + lane], poolacc);
    if (lane == 0) atomicAdd(&cntg[gcur], ccur);
#endif
}

// ---------------- head: mean, relu MLP, logits ----------------
__global__ void head_kernel(const float* __restrict__ pool, const float* __restrict__ cntg,
                            const float* __restrict__ W3, const float* __restrict__ b3,
                            const float* __restrict__ W4, const float* __restrict__ b4,
                            float* __restrict__ out)
{
    int g = threadIdx.x;
    if (g >= G_GRAPHS) return;
    float invc = 1.f / fmaxf(cntg[g], 1.f);
    float emb[HID];
#pragma unroll
    for (int k = 0; k < HID; ++k) emb[k] = pool[g * HID + k] * invc;
    float z[32];
    for (int j = 0; j < 32; ++j) {
        float s = b3[j];
        for (int k = 0; k < HID; ++k) s += emb[k] * W3[k * 32 + j];
        z[j] = fmaxf(s, 0.f);
    }
    for (int d = 0; d < 2; ++d) {
        float s = b4[d];
        for (int j = 0; j < 32; ++j) s += z[j] * W4[j * 2 + d];
        out[g * 2 + d] = s;
    }
}

extern "C" void kernel_launch(void* const* d_in, const int* in_sizes, int n_in,
                              void* d_out, int out_size, void* d_ws, size_t ws_size,
                              hipStream_t stream)
{
    const float* x     = (const float*)d_in[0];
    const int*   ei    = (const int*)d_in[1];
    const int*   batch = (const int*)d_in[2];
    const float* W1    = (const float*)d_in[3];
    const float* as1w  = (const float*)d_in[4];
    const float* ad1w  = (const float*)d_in[5];
    const float* b1    = (const float*)d_in[6];
    const float* W2    = (const float*)d_in[7];
    const float* as2w  = (const float*)d_in[8];
    const float* ad2w  = (const float*)d_in[9];
    const float* b2    = (const float*)d_in[10];
    const float* W3    = (const float*)d_in[11];
    const float* b3    = (const float*)d_in[12];
    const float* W4    = (const float*)d_in[13];
    const float* b4    = (const float*)d_in[14];
    float* out = (float*)d_out;

    char* ws = (char*)d_ws;
    size_t o = 0;
    auto alloc = [&](size_t bytes) -> void* {
        void* p = ws + o;
        o += (bytes + 255) & ~(size_t)255;
        return p;
    };
    unsigned short* h1b = (unsigned short*)alloc((size_t)N_NODES * D1 * 2);   // bf16 x@W1
    float*          hE  = (float*)alloc((size_t)N_NODES * D1 * 4);            // fp32 elu(agg1)
    unsigned short* h2b = (unsigned short*)alloc((size_t)N_NODES * HID * 2);  // bf16 hE@W2
    float* a_s1 = (float*)alloc((size_t)N_NODES * 4 * 4);
    float* a_d1 = (float*)alloc((size_t)N_NODES * 4 * 4);
    float* a_s2 = (float*)alloc((size_t)N_NODES * 4);
    float* a_d2 = (float*)alloc((size_t)N_NODES * 4);
    int*   deg    = (int*)alloc((size_t)N_NODES * 4);
    int*   incl   = (int*)alloc((size_t)N_NODES * 4);
    int*   offv   = (int*)alloc((size_t)N_NODES * 4);
    int*   cursor = (int*)alloc((size_t)N_NODES * 4);
    int*   bsum   = (int*)alloc(128 * 4);
    int*   bex    = (int*)alloc(128 * 4);
    int*   csr    = (int*)alloc((size_t)E_TOT * 4);
    float* pool   = (float*)alloc((size_t)G_GRAPHS * HID * 4);
    float* cntg   = (float*)alloc((size_t)G_GRAPHS * 4);

    (void)hipMemsetAsync(deg, 0, (size_t)N_NODES * 4, stream);
    (void)hipMemsetAsync(pool, 0, (size_t)G_GRAPHS * HID * 4, stream);
    (void)hipMemsetAsync(cntg, 0, (size_t)G_GRAPHS * 4, stream);

    const int nblk_nodes = (N_NODES + 3) / 4;
    const int nscan = (N_NODES + SCAN_B - 1) / SCAN_B;

    // GEMM1 + att1: h1b(bf16) = x @ W1 (Nc=256, 4 head col-tiles, astride=4)
    gemm_att<<<dim3(HEADS, (N_NODES + 127) / 128), 256, 0, stream>>>(
        x, W1, h1b, D1, as1w, ad1w, a_s1, a_d1, 4);

    // CSR build (shared by both layers)
    edge_hist<<<4096, 256, 0, stream>>>(ei, deg);
    scan_block<<<nscan, SCAN_B, 0, stream>>>(deg, incl, bsum, N_NODES);
    scan_bsum<<<1, 128, 0, stream>>>(bsum, bex, nscan);
    finalize_off<<<(N_NODES + 255) / 256, 256, 0, stream>>>(deg, incl, bex, offv, cursor, N_NODES);
    edge_scatter<<<4096, 256, 0, stream>>>(ei, offv, cursor, csr);

    // layer-1 gather-aggregate (bf16 payload), fused softmax + b1 + ELU
    agg1_kernel<<<nblk_nodes, 256, 0, stream>>>(h1b, csr, offv, deg, a_s1, a_d1, b1, hE);

    // GEMM2 + att2: h2b(bf16) = hE @ W2 (Nc=64, single col-tile, astride=1)
    gemm_att<<<dim3(1, (N_NODES + 127) / 128), 256, 0, stream>>>(
        hE, W2, h2b, HID, as2w, ad2w, a_s2, a_d2, 1);

    // layer-2 gather-aggregate (bf16 payload) + register-accumulated mean-pool
    const int nwaves2 = (N_NODES + CHUNK2 - 1) / CHUNK2;
    agg2_pool_kernel<<<(nwaves2 + 3) / 4, 256, 0, stream>>>(h2b, csr, offv, deg, a_s2, a_d2, b2, batch, pool, cntg);

    // head MLP
    head_kernel<<<1, 64, 0, stream>>>(pool, cntg, W3, b3, W4, b4, out);
}

// Round 9
// 766.185 us; speedup vs baseline: 1.4656x; 1.1590x over previous
//
#include <hip/hip_runtime.h>
#include <math.h>

#define N_NODES 100000
#define E_EDGES 1600000
#define E_TOT   (E_EDGES + N_NODES)
#define G_GRAPHS 64
#define IN_DIM 256
#define HID 64
#define HEADS 4
#define D1 256            // HEADS*HID
#define NEG_SLOPE 0.2f
#define SCAN_B 1024
#define CHUNK2 16         // nodes per wave in agg2

typedef float nfloat4 __attribute__((ext_vector_type(4)));
typedef unsigned short nus4 __attribute__((ext_vector_type(4)));
typedef short bf16x8 __attribute__((ext_vector_type(8)));
typedef float f32x4 __attribute__((ext_vector_type(4)));

// bf16 <-> fp32 (RNE encode, exact shift decode)
__device__ __forceinline__ float bf2f(unsigned short u) {
    unsigned int t = ((unsigned int)u) << 16;
    return __builtin_bit_cast(float, t);
}
__device__ __forceinline__ unsigned short f2bf(float f) {
    unsigned int u = __builtin_bit_cast(unsigned int, f);
    u += 0x7FFF + ((u >> 16) & 1);
    return (unsigned short)(u >> 16);
}
__device__ __forceinline__ unsigned int pk2(float lo, float hi) {
    return (unsigned int)f2bf(lo) | ((unsigned int)f2bf(hi) << 16);
}

// ---------------- MFMA GEMM + fused attention dots, bf16 in/out ----------------
// C[M,Nc](bf16) = A[M,256] @ B[256,Nc](fp32 weights, converted in staging).
// Block: 128 rows x BN cols, 256 thr (4 waves), K-step 32, mfma_f32_16x16x32_bf16.
// LDS quad-major [q][row/col][8]: frag reads are 16 consecutive b128 lanes -> bank-uniform.
// A layout: A[m=lane&15][k=(lane>>4)*8+j]; B: B[k=(lane>>4)*8+j][n=lane&15];
// C/D: col=lane&15, row=(lane>>4)*4+reg  (per cdna_hip_programming.md §3, m89-verified).
template<int BN, bool ABF16>
__global__ __launch_bounds__(256) void gemm_mfma(const void* __restrict__ Ain,
                                                 const float* __restrict__ B,
                                                 unsigned short* __restrict__ C,
                                                 int Nc,
                                                 const float* __restrict__ att_src,
                                                 const float* __restrict__ att_dst,
                                                 float* __restrict__ a_srcO,
                                                 float* __restrict__ a_dstO,
                                                 int astride)
{
    constexpr int NCG = BN / 16;                  // col-groups
    __shared__ unsigned short alds[4][128][8];    // 8 KB
    __shared__ unsigned short blds[4][BN][8];     // 8/4 KB
    const int tid = threadIdx.x;
    const int lane = tid & 63, wv = tid >> 6;
    const int qd = lane >> 4, c16 = lane & 15;
    const int bm = blockIdx.y * 128, bn = blockIdx.x * BN;

    f32x4 acc[2][NCG];
#pragma unroll
    for (int i = 0; i < 2; ++i)
#pragma unroll
        for (int j = 0; j < NCG; ++j) acc[i][j] = (f32x4){0.f, 0.f, 0.f, 0.f};

    const int ar = tid >> 1, akh = tid & 1;       // A staging: row, k-half
    const int gm = bm + ar;

    for (int k0 = 0; k0 < 256; k0 += 32) {
        // ---- stage A (128 x 32) ----
        if (ABF16) {
            const unsigned short* Ab = (const unsigned short*)Ain + (size_t)gm * 256 + k0 + akh * 16;
            uint4 v0 = make_uint4(0, 0, 0, 0), v1 = v0;
            if (gm < N_NODES) { v0 = *(const uint4*)Ab; v1 = *(const uint4*)(Ab + 8); }
            *(uint4*)&alds[2 * akh][ar][0] = v0;
            *(uint4*)&alds[2 * akh + 1][ar][0] = v1;
        } else {
            const float* Af = (const float*)Ain + (size_t)gm * 256 + k0 + akh * 16;
            float4 f0, f1, f2, f3;
            if (gm < N_NODES) {
                f0 = ((const float4*)Af)[0]; f1 = ((const float4*)Af)[1];
                f2 = ((const float4*)Af)[2]; f3 = ((const float4*)Af)[3];
            } else { f0 = f1 = f2 = f3 = make_float4(0.f, 0.f, 0.f, 0.f); }
            uint4 p0 = make_uint4(pk2(f0.x, f0.y), pk2(f0.z, f0.w), pk2(f1.x, f1.y), pk2(f1.z, f1.w));
            uint4 p1 = make_uint4(pk2(f2.x, f2.y), pk2(f2.z, f2.w), pk2(f3.x, f3.y), pk2(f3.z, f3.w));
            *(uint4*)&alds[2 * akh][ar][0] = p0;
            *(uint4*)&alds[2 * akh + 1][ar][0] = p1;
        }
        // ---- stage B (32 x BN): coalesced k-strided loads, transpose-pack ----
#pragma unroll
        for (int qq = 0; qq < BN / 64; ++qq) {
            const int c = tid & (BN - 1);
            const int q = (tid / BN) * (BN / 64) + qq;
            const float* Bp = B + (size_t)(k0 + q * 8) * Nc + bn + c;
            float b0 = Bp[0 * Nc], b1 = Bp[1 * Nc], b2 = Bp[2 * Nc], b3 = Bp[3 * Nc];
            float b4 = Bp[4 * Nc], b5 = Bp[5 * Nc], b6 = Bp[6 * Nc], b7 = Bp[7 * Nc];
            uint4 pv = make_uint4(pk2(b0, b1), pk2(b2, b3), pk2(b4, b5), pk2(b6, b7));
            *(uint4*)&blds[q][c][0] = pv;
        }
        __syncthreads();

        bf16x8 af0 = *(const bf16x8*)&alds[qd][wv * 32 + c16][0];
        bf16x8 af1 = *(const bf16x8*)&alds[qd][wv * 32 + 16 + c16][0];
#pragma unroll
        for (int cg = 0; cg < NCG; ++cg) {
            bf16x8 bfr = *(const bf16x8*)&blds[qd][cg * 16 + c16][0];
            acc[0][cg] = __builtin_amdgcn_mfma_f32_16x16x32_bf16(af0, bfr, acc[0][cg], 0, 0, 0);
            acc[1][cg] = __builtin_amdgcn_mfma_f32_16x16x32_bf16(af1, bfr, acc[1][cg], 0, 0, 0);
        }
        __syncthreads();
    }

    // ---- epilogue: attention dots (fp32 acc) + bf16 C store ----
    float sv[NCG], dv[NCG];
#pragma unroll
    for (int cg = 0; cg < NCG; ++cg) {
        sv[cg] = att_src[bn + cg * 16 + c16];
        dv[cg] = att_dst[bn + cg * 16 + c16];
    }
#pragma unroll
    for (int rg = 0; rg < 2; ++rg) {
#pragma unroll
        for (int reg = 0; reg < 4; ++reg) {
            const int m = bm + wv * 32 + rg * 16 + qd * 4 + reg;
#pragma unroll
            for (int hh = 0; hh < NCG / 4; ++hh) {
                float ps = 0.f, pd = 0.f;
#pragma unroll
                for (int cg = 4 * hh; cg < 4 * hh + 4; ++cg) {
                    ps += acc[rg][cg][reg] * sv[cg];
                    pd += acc[rg][cg][reg] * dv[cg];
                }
#pragma unroll
                for (int o = 1; o < 16; o <<= 1) { ps += __shfl_xor(ps, o); pd += __shfl_xor(pd, o); }
                if (c16 == 0 && m < N_NODES) {
                    a_srcO[m * astride + (bn >> 6) + hh] = ps;
                    a_dstO[m * astride + (bn >> 6) + hh] = pd;
                }
            }
            if (m < N_NODES) {
#pragma unroll
                for (int cg = 0; cg < NCG; ++cg)
                    C[(size_t)m * Nc + bn + cg * 16 + c16] = f2bf(acc[rg][cg][reg]);
            }
        }
    }
}

// ---------------- CSR build: histogram, scan, scatter ----------------
__global__ void edge_hist(const int* __restrict__ ei, int* __restrict__ deg)
{
    for (int e = blockIdx.x * blockDim.x + threadIdx.x; e < E_TOT; e += gridDim.x * blockDim.x) {
        int d = (e < E_EDGES) ? ei[E_EDGES + e] : (e - E_EDGES);
        atomicAdd(&deg[d], 1);
    }
}

__global__ __launch_bounds__(SCAN_B) void scan_block(const int* __restrict__ deg,
                                                     int* __restrict__ incl,
                                                     int* __restrict__ bsum, int n)
{
    __shared__ int s[SCAN_B];
    int i = blockIdx.x * SCAN_B + threadIdx.x;
    int v = (i < n) ? deg[i] : 0;
    s[threadIdx.x] = v;
    __syncthreads();
    for (int off = 1; off < SCAN_B; off <<= 1) {
        int t = (threadIdx.x >= off) ? s[threadIdx.x - off] : 0;
        __syncthreads();
        s[threadIdx.x] += t;
        __syncthreads();
    }
    if (i < n) incl[i] = s[threadIdx.x];
    if (threadIdx.x == SCAN_B - 1) bsum[blockIdx.x] = s[SCAN_B - 1];
}

__global__ void scan_bsum(const int* __restrict__ bsum, int* __restrict__ bex, int nb)
{
    __shared__ int s[128];
    int i = threadIdx.x;
    int v = (i < nb) ? bsum[i] : 0;
    s[i] = v;
    __syncthreads();
    for (int off = 1; off < 128; off <<= 1) {
        int t = (i >= off) ? s[i - off] : 0;
        __syncthreads();
        s[i] += t;
        __syncthreads();
    }
    if (i < nb) bex[i] = s[i] - v;   // exclusive
}

__global__ void finalize_off(const int* __restrict__ deg, const int* __restrict__ incl,
                             const int* __restrict__ bex, int* __restrict__ off,
                             int* __restrict__ cursor, int n)
{
    int i = blockIdx.x * blockDim.x + threadIdx.x;
    if (i < n) { off[i] = incl[i] - deg[i] + bex[i / SCAN_B]; cursor[i] = 0; }
}

__global__ void edge_scatter(const int* __restrict__ ei, const int* __restrict__ off,
                             int* __restrict__ cursor, int* __restrict__ csr_src)
{
    for (int e = blockIdx.x * blockDim.x + threadIdx.x; e < E_TOT; e += gridDim.x * blockDim.x) {
        int s = (e < E_EDGES) ? ei[e] : (e - E_EDGES);
        int d = (e < E_EDGES) ? ei[E_EDGES + e] : (e - E_EDGES);
        int slot = off[d] + atomicAdd(&cursor[d], 1);
        csr_src[slot] = s;
    }
}

// ---------------- layer-1 aggregation: wave per node, bf16 payload, bf16 out ----------------
__global__ __launch_bounds__(256) void agg1_kernel(const unsigned short* __restrict__ h1b,
                                                   const int* __restrict__ csr_src,
                                                   const int* __restrict__ off,
                                                   const int* __restrict__ deg,
                                                   const float* __restrict__ a_src,
                                                   const float* __restrict__ a_dst,
                                                   const float* __restrict__ b1,
                                                   unsigned short* __restrict__ hEb)
{
    const int wave = threadIdx.x >> 6, lane = threadIdx.x & 63;
    const int n = blockIdx.x * 4 + wave;
    if (n >= N_NODES) return;
    const int h = lane >> 4;
    const float adn = a_dst[n * 4 + h];
    const int st = off[n], cnt = deg[n];
    float4 acc = make_float4(0.f, 0.f, 0.f, 0.f);
    float dsum = 0.f;

    int s_cur = csr_src[st];                           // deg >= 1 (self-loop)
    int s_nxt = (cnt > 1) ? csr_src[st + 1] : s_cur;
    float a_cur = a_src[s_cur * 4 + h];
    ushort4 v_cur = *(const ushort4*)(h1b + (size_t)s_cur * D1 + lane * 4);

    for (int j = 0; j < cnt; ++j) {
        float a_nxt = a_src[s_nxt * 4 + h];
        ushort4 v_nxt = *(const ushort4*)(h1b + (size_t)s_nxt * D1 + lane * 4);
        int s_n2 = (j + 2 < cnt) ? csr_src[st + j + 2] : s_nxt;

        float al = a_cur + adn;
        al = (al > 0.f) ? al : NEG_SLOPE * al;
        float ex = __expf(al);
        dsum += ex;
        acc.x += ex * bf2f(v_cur.x); acc.y += ex * bf2f(v_cur.y);
        acc.z += ex * bf2f(v_cur.z); acc.w += ex * bf2f(v_cur.w);

        a_cur = a_nxt; v_cur = v_nxt; s_nxt = s_n2;
    }
    const float inv = 1.f / (dsum + 1e-16f);
    float4 bb = *(const float4*)(b1 + lane * 4);
    float ox = acc.x * inv + bb.x;
    float oy = acc.y * inv + bb.y;
    float oz = acc.z * inv + bb.z;
    float ow = acc.w * inv + bb.w;
    ox = (ox > 0.f) ? ox : expm1f(ox);
    oy = (oy > 0.f) ? oy : expm1f(oy);
    oz = (oz > 0.f) ? oz : expm1f(oz);
    ow = (ow > 0.f) ? ow : expm1f(ow);
    nus4 ob = { f2bf(ox), f2bf(oy), f2bf(oz), f2bf(ow) };
    __builtin_nontemporal_store(ob, (nus4*)(hEb + (size_t)n * D1 + lane * 4));
}

// ---------------- layer-2 aggregation + register-accumulated mean-pool (bf16 payload) ----------------
__global__ __launch_bounds__(256) void agg2_pool_kernel(const unsigned short* __restrict__ h2b,
                                                        const int* __restrict__ csr_src,
                                                        const int* __restrict__ off,
                                                        const int* __restrict__ deg,
                                                        const float* __restrict__ a_src,
                                                        const float* __restrict__ a_dst,
                                                        const float* __restrict__ b2,
                                                        const int* __restrict__ batch,
                                                        float* __restrict__ pool,
                                                        float* __restrict__ cntg)
{
    const int wave = threadIdx.x >> 6, lane = threadIdx.x & 63;
    const int wgid = blockIdx.x * 4 + wave;
    const int n0 = wgid * CHUNK2;
    if (n0 >= N_NODES) return;
    const int n1 = (n0 + CHUNK2 < N_NODES) ? n0 + CHUNK2 : N_NODES;
    const float bb = b2[lane];

    float poolacc = 0.f, ccur = 0.f;
    int gcur = batch[n0];

    for (int n = n0; n < n1; ++n) {
        const float adn = a_dst[n];
        const int st = off[n], cnt = deg[n];
        float acc = 0.f, dsum = 0.f;
        const int npairs = cnt >> 1;

        if (npairs > 0) {
            int s0 = csr_src[st], s1 = csr_src[st + 1];
            float A0 = a_src[s0], A1 = a_src[s1];
            unsigned short V0 = h2b[(size_t)s0 * HID + lane], V1 = h2b[(size_t)s1 * HID + lane];
            for (int p = 0; p < npairs; ++p) {
                int q = (p + 1 < npairs) ? st + 2 * (p + 1) : st;   // dummy=pair0 (cache-hot)
                int ns0 = csr_src[q], ns1 = csr_src[q + 1];
                float nA0 = a_src[ns0], nA1 = a_src[ns1];
                unsigned short nV0 = h2b[(size_t)ns0 * HID + lane], nV1 = h2b[(size_t)ns1 * HID + lane];

                float al0 = A0 + adn; al0 = (al0 > 0.f) ? al0 : NEG_SLOPE * al0;
                float al1 = A1 + adn; al1 = (al1 > 0.f) ? al1 : NEG_SLOPE * al1;
                float e0 = __expf(al0), e1 = __expf(al1);
                dsum += e0 + e1;
                acc += e0 * bf2f(V0) + e1 * bf2f(V1);

                A0 = nA0; V0 = nV0; A1 = nA1; V1 = nV1;
            }
        }
        if (cnt & 1) {                    // tail edge
            int s = csr_src[st + cnt - 1];
            float a = a_src[s];
            float v = bf2f(h2b[(size_t)s * HID + lane]);
            float al = a + adn; al = (al > 0.f) ? al : NEG_SLOPE * al;
            float e = __expf(al);
            dsum += e; acc += e * v;
        }

        float val = acc / (dsum + 1e-16f) + bb;
        int g = batch[n];
        if (g != gcur) {
#if defined(__AMDGCN__)
            unsafeAtomicAdd(&pool[gcur * HID + lane], poolacc);
            if (lane == 0) unsafeAtomicAdd(&cntg[gcur], ccur);
#else
            atomicAdd(&pool[gcur * HID + lane], poolacc);
            if (lane == 0) atomicAdd(&cntg[gcur], ccur);
#endif
            poolacc = 0.f; ccur = 0.f; gcur = g;
        }
        poolacc += val;
        ccur += 1.f;
    }
#if defined(__AMDGCN__)
    unsafeAtomicAdd(&pool[gcur * HID + lane], poolacc);
    if (lane == 0) unsafeAtomicAdd(&cntg[gcur], ccur);
#else
    atomicAdd(&pool[gcur * HID + lane], poolacc);
    if (lane == 0) atomicAdd(&cntg[gcur], ccur);
#endif
}

// ---------------- head: mean, relu MLP, logits ----------------
__global__ void head_kernel(const float* __restrict__ pool, const float* __restrict__ cntg,
                            const float* __restrict__ W3, const float* __restrict__ b3,
                            const float* __restrict__ W4, const float* __restrict__ b4,
                            float* __restrict__ out)
{
    int g = threadIdx.x;
    if (g >= G_GRAPHS) return;
    float invc = 1.f / fmaxf(cntg[g], 1.f);
    float emb[HID];
#pragma unroll
    for (int k = 0; k < HID; ++k) emb[k] = pool[g * HID + k] * invc;
    float z[32];
    for (int j = 0; j < 32; ++j) {
        float s = b3[j];
        for (int k = 0; k < HID; ++k) s += emb[k] * W3[k * 32 + j];
        z[j] = fmaxf(s, 0.f);
    }
    for (int d = 0; d < 2; ++d) {
        float s = b4[d];
        for (int j = 0; j < 32; ++j) s += z[j] * W4[j * 2 + d];
        out[g * 2 + d] = s;
    }
}

extern "C" void kernel_launch(void* const* d_in, const int* in_sizes, int n_in,
                              void* d_out, int out_size, void* d_ws, size_t ws_size,
                              hipStream_t stream)
{
    const float* x     = (const float*)d_in[0];
    const int*   ei    = (const int*)d_in[1];
    const int*   batch = (const int*)d_in[2];
    const float* W1    = (const float*)d_in[3];
    const float* as1w  = (const float*)d_in[4];
    const float* ad1w  = (const float*)d_in[5];
    const float* b1    = (const float*)d_in[6];
    const float* W2    = (const float*)d_in[7];
    const float* as2w  = (const float*)d_in[8];
    const float* ad2w  = (const float*)d_in[9];
    const float* b2    = (const float*)d_in[10];
    const float* W3    = (const float*)d_in[11];
    const float* b3    = (const float*)d_in[12];
    const float* W4    = (const float*)d_in[13];
    const float* b4    = (const float*)d_in[14];
    float* out = (float*)d_out;

    char* ws = (char*)d_ws;
    size_t o = 0;
    auto alloc = [&](size_t bytes) -> void* {
        void* p = ws + o;
        o += (bytes + 255) & ~(size_t)255;
        return p;
    };
    unsigned short* h1b = (unsigned short*)alloc((size_t)N_NODES * D1 * 2);   // bf16 x@W1
    unsigned short* hEb = (unsigned short*)alloc((size_t)N_NODES * D1 * 2);   // bf16 elu(agg1)
    unsigned short* h2b = (unsigned short*)alloc((size_t)N_NODES * HID * 2);  // bf16 hE@W2
    float* a_s1 = (float*)alloc((size_t)N_NODES * 4 * 4);
    float* a_d1 = (float*)alloc((size_t)N_NODES * 4 * 4);
    float* a_s2 = (float*)alloc((size_t)N_NODES * 4);
    float* a_d2 = (float*)alloc((size_t)N_NODES * 4);
    int*   deg    = (int*)alloc((size_t)N_NODES * 4);
    int*   incl   = (int*)alloc((size_t)N_NODES * 4);
    int*   offv   = (int*)alloc((size_t)N_NODES * 4);
    int*   cursor = (int*)alloc((size_t)N_NODES * 4);
    int*   bsum   = (int*)alloc(128 * 4);
    int*   bex    = (int*)alloc(128 * 4);
    int*   csr    = (int*)alloc((size_t)E_TOT * 4);
    float* pool   = (float*)alloc((size_t)G_GRAPHS * HID * 4);
    float* cntg   = (float*)alloc((size_t)G_GRAPHS * 4);

    (void)hipMemsetAsync(deg, 0, (size_t)N_NODES * 4, stream);
    (void)hipMemsetAsync(pool, 0, (size_t)G_GRAPHS * HID * 4, stream);
    (void)hipMemsetAsync(cntg, 0, (size_t)G_GRAPHS * 4, stream);

    const int nblk_nodes = (N_NODES + 3) / 4;
    const int nscan = (N_NODES + SCAN_B - 1) / SCAN_B;
    const int nrowblk = (N_NODES + 127) / 128;

    // GEMM1 + att1 (MFMA): h1b = bf16(x) @ bf16(W1), 2 col-tiles of 128
    gemm_mfma<128, false><<<dim3(2, nrowblk), 256, 0, stream>>>(
        x, W1, h1b, D1, as1w, ad1w, a_s1, a_d1, 4);

    // CSR build (shared by both layers)
    edge_hist<<<4096, 256, 0, stream>>>(ei, deg);
    scan_block<<<nscan, SCAN_B, 0, stream>>>(deg, incl, bsum, N_NODES);
    scan_bsum<<<1, 128, 0, stream>>>(bsum, bex, nscan);
    finalize_off<<<(N_NODES + 255) / 256, 256, 0, stream>>>(deg, incl, bex, offv, cursor, N_NODES);
    edge_scatter<<<4096, 256, 0, stream>>>(ei, offv, cursor, csr);

    // layer-1 gather-aggregate (bf16 payload), fused softmax + b1 + ELU, bf16 out
    agg1_kernel<<<nblk_nodes, 256, 0, stream>>>(h1b, csr, offv, deg, a_s1, a_d1, b1, hEb);

    // GEMM2 + att2 (MFMA): h2b = hEb @ bf16(W2), single 64-col tile
    gemm_mfma<64, true><<<dim3(1, nrowblk), 256, 0, stream>>>(
        hEb, W2, h2b, HID, as2w, ad2w, a_s2, a_d2, 1);

    // layer-2 gather-aggregate (bf16 payload) + register-accumulated mean-pool
    const int nwaves2 = (N_NODES + CHUNK2 - 1) / CHUNK2;
    agg2_pool_kernel<<<(nwaves2 + 3) / 4, 256, 0, stream>>>(h2b, csr, offv, deg, a_s2, a_d2, b2, batch, pool, cntg);

    // head MLP
    head_kernel<<<1, 64, 0, stream>>>(pool, cntg, W3, b3, W4, b4, out);
}